// Round 1
// 299.813 us; speedup vs baseline: 1.0365x; 1.0365x over previous
//
#include <hip/hip_runtime.h>
#include <hip/hip_bf16.h>
#include <cmath>
#include <cstring>

#define B_SZ   512
#define SLEN   1000
#define DD     16
#define HID    256
#define WIN    64
#define PAIRS  120
#define LSIG   136
#define NWIN   20
#define MAXST  21
#define K1P    416     // layer-1 K padded to x32
#define W1FN   (13 * 16 * 64 * 8)   // 106496 elems
#define WFN    (8 * 16 * 64 * 8)    // 65536 elems (W2/W3/Wl)

using short8 = __attribute__((ext_vector_type(8))) short;
using half8  = __attribute__((ext_vector_type(8))) _Float16;
using f32x4  = __attribute__((ext_vector_type(4))) float;

struct SchedArgs { short snapk[SLEN - 1]; };
struct CombArgs  { unsigned char winofm[WIN]; unsigned char zl[WIN]; };
struct ChainArgs { int nsteps; unsigned char kU[32]; };
struct FuseArgs  { unsigned char sidx[WIN]; };

__device__ __forceinline__ unsigned short f2h(float x) {
  _Float16 h = (_Float16)x;
  return __builtin_bit_cast(unsigned short, h);
}
__device__ __forceinline__ float ftanh(float x) {   // clamped; |err|~1e-6
  float t = fminf(fmaxf(2.f * x, -30.f), 30.f);
  float e = __expf(t);
  return (e - 1.f) / (e + 1.f);
}

// ---------------------------------------------------------------- prep: win scan + weight frag convert
// grid (NWIN+3, B_SZ) x 128. Blocks w<NWIN: per-window Levy scan. Else: convert
// W1/W2/W3/Wl -> fp16 MFMA B-frag layout:
//   Wf[(kk*16+nsub)*64+lane][j] = W[nsub*16+(lane&15)][kk*32+(lane>>4)*8+j]
__global__ __launch_bounds__(128) void prep_kernel(
    const float* __restrict__ z,
    const float* __restrict__ W1, const float* __restrict__ W2,
    const float* __restrict__ W3, const float* __restrict__ Wl,
    float* __restrict__ logsig, float* __restrict__ dxwin,
    unsigned short* __restrict__ W1f, unsigned short* __restrict__ W2f,
    unsigned short* __restrict__ W3f, unsigned short* __restrict__ Wlf,
    SchedArgs A)
{
  const int w = blockIdx.x, b = blockIdx.y, tid = threadIdx.x;
  if (w >= NWIN) {                                   // ---- weight conversion
    const int slot = ((w - NWIN) * B_SZ + b) * 128 + tid;   // 196608 slots
    for (int e = slot; e < W1FN + 3 * WFN; e += 3 * B_SZ * 128) {
      if (e < W1FN) {
        int f = e;
        int j = f & 7, l15 = (f >> 3) & 15, lq = (f >> 7) & 3, nsub = (f >> 9) & 15, kk = f >> 13;
        int row = nsub * 16 + l15, col = kk * 32 + lq * 8 + j;
        float v = (col < HID + LSIG) ? W1[(size_t)row * (HID + LSIG) + col] : 0.f;
        W1f[f] = f2h(v);
      } else {
        int e2 = e - W1FN;
        int which = e2 >> 16, f = e2 & 65535;
        int j = f & 7, l15 = (f >> 3) & 15, lq = (f >> 7) & 3, nsub = (f >> 9) & 15, kk = (f >> 13) & 7;
        int row = nsub * 16 + l15, col = kk * 32 + lq * 8 + j;
        const float* src = which == 0 ? W2 : which == 1 ? W3 : Wl;
        unsigned short* dst = which == 0 ? W2f : which == 1 ? W3f : Wlf;
        dst[f] = f2h(src[(size_t)row * HID + col]);
      }
    }
    return;
  }
  // ---- per-window Levy scan (dtsqrt inlined)
  __shared__ float zs[50][16];
  const int ns = (w == NWIN - 1) ? 49 : 50;
  const float* src = z + ((size_t)b * SLEN + 50 * w + 1) * DD;
  const double s999 = 1.0 / (double)(SLEN - 1);
  for (int c = tid; c < ns * 4; c += 128) {
    float4 v = ((const float4*)src)[c];
    int t = 50 * w + (c >> 2);
    double a = (t + 1 == SLEN - 1) ? 1.0 : (double)(t + 1) * s999;
    float s = sqrtf((float)(a - (double)t * s999));
    v.x *= s; v.y *= s; v.z *= s; v.w *= s;
    ((float4*)&zs[0][0])[c] = v;
  }
  int pi = 0, pj = 0;
  if (tid < PAIRS) { int rem = tid, i = 0; while (rem >= DD - 1 - i) { rem -= DD - 1 - i; ++i; } pi = i; pj = i + 1 + rem; }
  __syncthreads();
  float Yi = 0.f, Yj = 0.f, LL = 0.f, Yd = 0.f;
  const int base_t = 50 * w;
  for (int u = 0; u < ns; ++u) {
    const float di = zs[u][pi], dj = zs[u][pj];
    LL = fmaf(Yi, dj, LL); LL = fmaf(-Yj, di, LL);
    Yi += di; Yj += dj;
    if (tid < DD) Yd += zs[u][tid];
    const int m = A.snapk[base_t + u];
    if (m) {
      float* dst = logsig + ((size_t)b * WIN + m) * LSIG;
      if (tid < DD)    dst[tid]      = Yd;
      if (tid < PAIRS) dst[DD + tid] = LL;
    }
  }
  if (tid < DD) dxwin[((size_t)b * NWIN + w) * DD + tid] = Yd;
}

// ---------------------------------------------------------------- combine windows (fully parallel)
__global__ __launch_bounds__(128) void comb_kernel(
    float* __restrict__ logsig, const float* __restrict__ dxwin, CombArgs A)
{
  const int m = blockIdx.x, b = blockIdx.y, tid = threadIdx.x;
  float* row = logsig + ((size_t)b * WIN + m) * LSIG;
  if (m == 0) {
    if (tid < LSIG) row[tid] = 0.f;
    if (tid + 128 < LSIG) row[tid + 128] = 0.f;
    return;
  }
  __shared__ float Xs[DD], Yt[DD];
  const int w = A.winofm[m];
  if (tid < DD) {
    float acc = 0.f;
    for (int ww = 0; ww < w; ++ww) acc += dxwin[((size_t)b * NWIN + ww) * DD + tid];
    float y = row[tid];
    Xs[tid] = acc; Yt[tid] = y;
    row[tid] = acc + y;
  }
  __syncthreads();
  if (tid < PAIRS) {
    int rem = tid, i = 0; while (rem >= DD - 1 - i) { rem -= DD - 1 - i; ++i; }
    const int pi = i, pj = i + 1 + rem;
    float ll = row[DD + tid];
    row[DD + tid] = A.zl[m] ? 0.f : 0.5f * (ll + Xs[pi] * Yt[pj] - Xs[pj] * Yt[pi]);
  }
}

// ---------------------------------------------------------------- sequential state chain (fp16 MFMA)
// 32 blocks x 512 thr (8 waves). M=16 rows/block; wave w owns cols [32w,32w+32).
// The 512-thr block forces 2 waves/SIMD, so the HW VGPR budget is 256/wave
// (pool halves at 64/128/256). amdgpu_waves_per_eu(2,2) pins the compiler to
// that budget (its default heuristic capped at 128 and spilled reg-resident
// weights). W1 (26 frags = 104 VGPR) + W3 (16 frags = 64 VGPR) now live in
// registers across ALL steps; W2 frags stay in LDS (128 KB, loaded once).
// This removes the ~336 KB/step per-block L2 weight restream that sat on the
// sequential critical path. Chunk-of-8 activation layout -> conflict-free
// ds_read_b128. 3 barriers/step (minimum: inter-layer deps span waves).
__global__ __attribute__((amdgpu_flat_work_group_size(512, 512)))
__attribute__((amdgpu_waves_per_eu(2, 2)))
void chain_kernel(
    const float* __restrict__ logsig,
    const unsigned short* __restrict__ W1f, const unsigned short* __restrict__ W2f,
    const unsigned short* __restrict__ W3f,
    const float* __restrict__ b1, const float* __restrict__ b2, const float* __restrict__ b3,
    unsigned short* __restrict__ statesb, ChainArgs A)
{
  __shared__ __align__(16) unsigned short A0s[52 * 16 * 8];   // 13.0 KB
  __shared__ __align__(16) unsigned short A1s[32 * 16 * 8];   //  8 KB
  __shared__ __align__(16) unsigned short A2s[32 * 16 * 8];   //  8 KB
  __shared__ __align__(16) unsigned short W2L[WFN];           // 128 KB
  const int tid = threadIdx.x, g = blockIdx.x;
  const int lane = tid & 63, w = tid >> 6;
  const int l15 = lane & 15, lq = lane >> 4;

  for (int c = tid; c < 52 * 16 * 8; c += 512) A0s[c] = 0;
  for (int c = tid; c < 16 * HID; c += 512) {
    int r = c >> 8, col = c & 255;
    statesb[((size_t)(g * 16 + r) * MAXST + 0) * HID + col] = 0;
  }
  for (int c = tid; c < WFN / 8; c += 512)            // W2 frags -> LDS (once)
    *(short8*)&W2L[c * 8] = *(const short8*)(W2f + (size_t)c * 8);

  // ---- W1/W3 frags -> registers (once, resident across all steps)
  half8 W1r[26];
#pragma unroll
  for (int kk = 0; kk < 13; ++kk)
#pragma unroll
    for (int nt = 0; nt < 2; ++nt)
      W1r[kk * 2 + nt] = *(const half8*)(W1f + ((size_t)(kk * 16 + w * 2 + nt) * 64 + lane) * 8);
  half8 W3r[16];
#pragma unroll
  for (int kk = 0; kk < 8; ++kk)
#pragma unroll
    for (int nt = 0; nt < 2; ++nt)
      W3r[kk * 2 + nt] = *(const half8*)(W3f + ((size_t)(kk * 16 + w * 2 + nt) * 64 + lane) * 8);

  float bias1[2], bias2[2], bias3[2];
#pragma unroll
  for (int nt = 0; nt < 2; ++nt) {
    int col = (w * 2 + nt) * 16 + l15;
    bias1[nt] = b1[col]; bias2[nt] = b2[col]; bias3[nt] = b3[col];
  }
  // logsig staging plumbing (chunk-of-8 target region, cols 256..391)
  int gofs[5]; int a0off[5]; int nld = 0;
#pragma unroll
  for (int i = 0; i < 5; ++i) {
    int c = tid + 512 * i;
    if (c < 16 * LSIG) {
      int r = c / LSIG, cc = c - r * LSIG;
      gofs[i] = ((g * 16 + r) * WIN) * LSIG + cc;
      a0off[i] = (((HID + cc) >> 3) * 16 + r) * 8 + ((HID + cc) & 7);
      nld = i + 1;
    }
  }
  float lsr[5];
  {
    const int k0 = A.kU[0];
    for (int i = 0; i < nld; ++i) lsr[i] = logsig[gofs[i] + k0 * LSIG];
  }
  __syncthreads();
  for (int i = 0; i < nld; ++i) A0s[a0off[i]] = f2h(lsr[i]);
  __syncthreads();

  for (int m = 0; m < A.nsteps; ++m) {
    if (m + 1 < A.nsteps) {
      const int kn = A.kU[m + 1];
      for (int i = 0; i < nld; ++i) lsr[i] = logsig[gofs[i] + kn * LSIG];
    }
    // ---- L1: K=416, W1 frags from registers
    {
      f32x4 acc[2][2] = {{{0.f,0.f,0.f,0.f},{0.f,0.f,0.f,0.f}},{{0.f,0.f,0.f,0.f},{0.f,0.f,0.f,0.f}}};
#pragma unroll
      for (int kk = 0; kk < 13; ++kk) {
        half8 af = *(const half8*)&A0s[((kk * 4 + lq) * 16 + l15) * 8];
        acc[kk & 1][0] = __builtin_amdgcn_mfma_f32_16x16x32_f16(af, W1r[kk * 2    ], acc[kk & 1][0], 0, 0, 0);
        acc[kk & 1][1] = __builtin_amdgcn_mfma_f32_16x16x32_f16(af, W1r[kk * 2 + 1], acc[kk & 1][1], 0, 0, 0);
      }
#pragma unroll
      for (int nt = 0; nt < 2; ++nt) {
        f32x4 s = acc[0][nt] + acc[1][nt];
        int col = w * 32 + nt * 16 + l15;
        int base = ((col >> 3) * 16) * 8 + (col & 7);
#pragma unroll
        for (int r4 = 0; r4 < 4; ++r4)
          A1s[base + (lq * 4 + r4) * 8] = f2h(fmaxf(s[r4] + bias1[nt], 0.f));
      }
    }
    __syncthreads();
    if (m + 1 < A.nsteps)                       // stage logsig(m+1): visible after L3 barrier
      for (int i = 0; i < nld; ++i) A0s[a0off[i]] = f2h(lsr[i]);
    // ---- L2: K=256, W2 frags from LDS
    {
      f32x4 acc[2][2] = {{{0.f,0.f,0.f,0.f},{0.f,0.f,0.f,0.f}},{{0.f,0.f,0.f,0.f},{0.f,0.f,0.f,0.f}}};
#pragma unroll
      for (int kk = 0; kk < 8; ++kk) {
        half8 af = *(const half8*)&A1s[((kk * 4 + lq) * 16 + l15) * 8];
        half8 bf0 = *(const half8*)&W2L[((kk * 16 + w * 2    ) * 64 + lane) * 8];
        half8 bf1 = *(const half8*)&W2L[((kk * 16 + w * 2 + 1) * 64 + lane) * 8];
        acc[kk & 1][0] = __builtin_amdgcn_mfma_f32_16x16x32_f16(af, bf0, acc[kk & 1][0], 0, 0, 0);
        acc[kk & 1][1] = __builtin_amdgcn_mfma_f32_16x16x32_f16(af, bf1, acc[kk & 1][1], 0, 0, 0);
      }
#pragma unroll
      for (int nt = 0; nt < 2; ++nt) {
        f32x4 s = acc[0][nt] + acc[1][nt];
        int col = w * 32 + nt * 16 + l15;
        int base = ((col >> 3) * 16) * 8 + (col & 7);
#pragma unroll
        for (int r4 = 0; r4 < 4; ++r4)
          A2s[base + (lq * 4 + r4) * 8] = f2h(fmaxf(s[r4] + bias2[nt], 0.f));
      }
    }
    __syncthreads();
    // ---- L3: K=256, W3 frags from registers; fast tanh -> A0 state + export fp16
    {
      f32x4 acc[2][2] = {{{0.f,0.f,0.f,0.f},{0.f,0.f,0.f,0.f}},{{0.f,0.f,0.f,0.f},{0.f,0.f,0.f,0.f}}};
#pragma unroll
      for (int kk = 0; kk < 8; ++kk) {
        half8 af = *(const half8*)&A2s[((kk * 4 + lq) * 16 + l15) * 8];
        acc[kk & 1][0] = __builtin_amdgcn_mfma_f32_16x16x32_f16(af, W3r[kk * 2    ], acc[kk & 1][0], 0, 0, 0);
        acc[kk & 1][1] = __builtin_amdgcn_mfma_f32_16x16x32_f16(af, W3r[kk * 2 + 1], acc[kk & 1][1], 0, 0, 0);
      }
#pragma unroll
      for (int nt = 0; nt < 2; ++nt) {
        f32x4 s = acc[0][nt] + acc[1][nt];
        int col = w * 32 + nt * 16 + l15;
        int base = ((col >> 3) * 16) * 8 + (col & 7);
#pragma unroll
        for (int r4 = 0; r4 < 4; ++r4) {
          int row = lq * 4 + r4;
          float tv = ftanh(s[r4] + bias3[nt]);
          unsigned short hv = f2h(tv);
          A0s[base + row * 8] = hv;
          statesb[((size_t)(g * 16 + row) * MAXST + (m + 1)) * HID + col] = hv;
        }
      }
    }
    __syncthreads();
  }
}

// ---------------------------------------------------------------- fused batched MLP (fp16 MFMA)
// 256 blocks x 256 thr (4 waves, 1 wave/SIMD -> full VGPR headroom). 128 rows
// (2 batch rows x 64 steps) x all 4 layers. Wave w owns n-tiles w*4..w*4+3
// (64 cols) x all 8 m-tiles -> acc[8][4], no duplicate B reads across waves.
// B-frags straight from L2 (pre-fragmented, 1KB/inst, each read once/block).
// Acts in chunk-of-8 LDS (conflict-free). Barriers: 13 (L1 A-staging, double-
// buffered) + 3 inter-layer  (was ~148).
__global__ __launch_bounds__(256, 1) void fused_kernel(
    const unsigned short* __restrict__ statesb, const float* __restrict__ logsig,
    const unsigned short* __restrict__ W1f, const unsigned short* __restrict__ W2f,
    const unsigned short* __restrict__ W3f, const unsigned short* __restrict__ Wlf,
    const float* __restrict__ b1, const float* __restrict__ b2, const float* __restrict__ b3,
    float* __restrict__ out, FuseArgs F)
{
  __shared__ __align__(16) unsigned short act1[32 * 128 * 8];   // 64 KB, chunk-8 [col>>3][row][col&7]
  __shared__ __align__(16) unsigned short act2[32 * 128 * 8];   // 64 KB
  __shared__ __align__(16) unsigned short atile[2][4 * 128 * 8];// 2 x 8 KB
  const int tid = threadIdx.x, band = blockIdx.x;
  const int lane = tid & 63, w = tid >> 6;
  const int l15 = lane & 15, lq = lane >> 4;

  float bias1[4], bias2[4], bias3[4];
#pragma unroll
  for (int t = 0; t < 4; ++t) {
    int col = w * 64 + t * 16 + l15;
    bias1[t] = b1[col]; bias2[t] = b2[col]; bias3[t] = b3[col];
  }

  // ---- L1: K=416, A staged per-kk (dbuf), B-frags from L2
  f32x4 acc[8][4];
#pragma unroll
  for (int a = 0; a < 8; ++a)
#pragma unroll
    for (int t = 0; t < 4; ++t) acc[a][t] = (f32x4){0.f, 0.f, 0.f, 0.f};

  short8 pk[2];
  auto loadA = [&](int kk, short8* p) {
#pragma unroll
    for (int i = 0; i < 2; ++i) {
      int c = tid + 256 * i;
      int r = c >> 2, cc = (c & 3) * 8;
      int col = kk * 32 + cc;
      int bA = band * 2 + (r >> 6), ks = r & 63;
      if (col < HID) {
        p[i] = *(const short8*)(statesb + ((size_t)bA * MAXST + F.sidx[ks]) * HID + col);
      } else {
        const float* sp = logsig + ((size_t)bA * WIN + ks) * LSIG + (col - HID); // tail reads past 136 benign (W pad=0)
        float4 v0 = ((const float4*)sp)[0];
        float4 v1 = ((const float4*)sp)[1];
        short8 q;
        q[0] = (short)f2h(v0.x); q[1] = (short)f2h(v0.y); q[2] = (short)f2h(v0.z); q[3] = (short)f2h(v0.w);
        q[4] = (short)f2h(v1.x); q[5] = (short)f2h(v1.y); q[6] = (short)f2h(v1.z); q[7] = (short)f2h(v1.w);
        p[i] = q;
      }
    }
  };
  loadA(0, pk);
  for (int kk = 0; kk < 13; ++kk) {
    unsigned short* buf = atile[kk & 1];
#pragma unroll
    for (int i = 0; i < 2; ++i) {
      int c = tid + 256 * i;
      int r = c >> 2, ch = c & 3;
      *(short8*)&buf[(ch * 128 + r) * 8] = pk[i];
    }
    __syncthreads();
    if (kk + 1 < 13) loadA(kk + 1, pk);       // issue early; hides under MFMAs
    half8 bfr[4];
#pragma unroll
    for (int t = 0; t < 4; ++t)
      bfr[t] = *(const half8*)(W1f + ((size_t)(kk * 16 + w * 4 + t) * 64 + lane) * 8);
#pragma unroll
    for (int a = 0; a < 8; ++a) {
      half8 af = *(const half8*)&buf[(lq * 128 + a * 16 + l15) * 8];
#pragma unroll
      for (int t = 0; t < 4; ++t)
        acc[a][t] = __builtin_amdgcn_mfma_f32_16x16x32_f16(af, bfr[t], acc[a][t], 0, 0, 0);
    }
    __syncthreads();
  }
#pragma unroll
  for (int a = 0; a < 8; ++a)
#pragma unroll
    for (int t = 0; t < 4; ++t) {
      int col = w * 64 + t * 16 + l15;
      int base = ((col >> 3) * 128) * 8 + (col & 7);
#pragma unroll
      for (int r4 = 0; r4 < 4; ++r4) {
        int row = a * 16 + lq * 4 + r4;
        act1[base + row * 8] = f2h(fmaxf(acc[a][t][r4] + bias1[t], 0.f));
      }
    }
  __syncthreads();

  // ---- generic K=256 layer: A from act LDS, B-frags from L2
  auto layer = [&](const unsigned short* inb, const unsigned short* Wf) {
#pragma unroll
    for (int a = 0; a < 8; ++a)
#pragma unroll
      for (int t = 0; t < 4; ++t) acc[a][t] = (f32x4){0.f, 0.f, 0.f, 0.f};
    for (int kk = 0; kk < 8; ++kk) {
      half8 bfr[4];
#pragma unroll
      for (int t = 0; t < 4; ++t)
        bfr[t] = *(const half8*)(Wf + ((size_t)(kk * 16 + w * 4 + t) * 64 + lane) * 8);
#pragma unroll
      for (int a = 0; a < 8; ++a) {
        half8 af = *(const half8*)&inb[((kk * 4 + lq) * 128 + a * 16 + l15) * 8];
#pragma unroll
        for (int t = 0; t < 4; ++t)
          acc[a][t] = __builtin_amdgcn_mfma_f32_16x16x32_f16(af, bfr[t], acc[a][t], 0, 0, 0);
      }
    }
  };

  layer(act1, W2f);                                   // L2 -> relu -> act2
#pragma unroll
  for (int a = 0; a < 8; ++a)
#pragma unroll
    for (int t = 0; t < 4; ++t) {
      int col = w * 64 + t * 16 + l15;
      int base = ((col >> 3) * 128) * 8 + (col & 7);
#pragma unroll
      for (int r4 = 0; r4 < 4; ++r4) {
        int row = a * 16 + lq * 4 + r4;
        act2[base + row * 8] = f2h(fmaxf(acc[a][t][r4] + bias2[t], 0.f));
      }
    }
  __syncthreads();

  layer(act2, W3f);                                   // L3 -> tanh -> act1
#pragma unroll
  for (int a = 0; a < 8; ++a)
#pragma unroll
    for (int t = 0; t < 4; ++t) {
      int col = w * 64 + t * 16 + l15;
      int base = ((col >> 3) * 128) * 8 + (col & 7);
#pragma unroll
      for (int r4 = 0; r4 < 4; ++r4) {
        int row = a * 16 + lq * 4 + r4;
        act1[base + row * 8] = f2h(ftanh(acc[a][t][r4] + bias3[t]));
      }
    }
  __syncthreads();

  layer(act1, Wlf);                                   // L4 -> fp32 out
#pragma unroll
  for (int a = 0; a < 8; ++a)
#pragma unroll
    for (int t = 0; t < 4; ++t) {
      int col = w * 64 + t * 16 + l15;
#pragma unroll
      for (int r4 = 0; r4 < 4; ++r4) {
        int row = a * 16 + lq * 4 + r4;
        out[((size_t)(band * 128 + row)) * HID + col] = acc[a][t][r4];
      }
    }
}

// ---------------------------------------------------------------- host schedule
static void build_sched(SchedArgs& P, CombArgs& CB, ChainArgs& CH, FuseArgs& FU) {
  double tb[SLEN], tt[WIN], tu[NWIN];
  const double s999 = 1.0 / (double)(SLEN - 1);
  const double s63  = 1.0 / (double)(WIN - 1);
  for (int i = 0; i < SLEN; ++i) tb[i] = (double)i * s999;
  tb[SLEN - 1] = 1.0;
  for (int k = 0; k < WIN; ++k) tt[k] = (double)k * s63;
  tt[WIN - 1] = 1.0;
  for (int j = 0; j < NWIN; ++j) tu[j] = tb[50 * j];

  int t_idx[WIN - 1], u_for_t[WIN - 1];
  for (int k = 1; k < WIN; ++k) {
    int ii = 0;
    for (int q = 0; q < SLEN; ++q) if (tb[q] <= tt[k]) ii = q;
    t_idx[k - 1] = ii;
    int jj = 0;
    for (int q = 0; q < NWIN; ++q) if (tu[q] <= tt[k]) jj = q;
    u_for_t[k - 1] = jj;
  }
  for (int t = 0; t < SLEN - 1; ++t) P.snapk[t] = 0;
  for (int m = 1; m < WIN; ++m) P.snapk[t_idx[m - 1] - 1] = (short)m;

  for (int m = 0; m < WIN; ++m) { CB.winofm[m] = 0; CB.zl[m] = 0; }
  for (int m = 1; m < WIN; ++m) {
    int p = t_idx[m - 1];
    CB.winofm[m] = (unsigned char)((p - 1) / 50);
    CB.zl[m] = (p % 50 == 0) ? 1 : 0;
  }

  double qt[32]; int nq = 0, last = -1;
  for (int m = 0; m < WIN - 1; ++m) {
    const int iu = u_for_t[m];
    if (iu != last) { qt[nq++] = tu[iu]; last = iu; }
  }
  qt[nq++] = tt[WIN - 1];
  int upd[WIN]; int qh = 0;
  for (int i = 0; i < WIN; ++i) {
    upd[i] = 0;
    if (qh < nq && tt[i] >= qt[qh]) { qh++; upd[i] = 1; }
  }
  int nU = 0;
  for (int k = 0; k < WIN; ++k) if (upd[k]) { if (nU < 32) CH.kU[nU] = (unsigned char)k; ++nU; }
  int cnt = 0;
  for (int k = 0; k < WIN; ++k) { FU.sidx[k] = (unsigned char)cnt; if (upd[k]) ++cnt; }
  CH.nsteps = FU.sidx[WIN - 1];
}

extern "C" void kernel_launch(void* const* d_in, const int* in_sizes, int n_in,
                              void* d_out, int out_size, void* d_ws, size_t ws_size,
                              hipStream_t stream) {
  const float* z  = (const float*)d_in[0];
  const float* W1 = (const float*)d_in[1];
  const float* b1 = (const float*)d_in[2];
  const float* W2 = (const float*)d_in[3];
  const float* b2 = (const float*)d_in[4];
  const float* W3 = (const float*)d_in[5];
  const float* b3 = (const float*)d_in[6];
  const float* Wl = (const float*)d_in[7];

  char* ws = (char*)d_ws;
  float* logsig = (float*)(ws);                                         // 17.83 MB
  size_t o = (size_t)B_SZ * WIN * LSIG * 4;
  float* dxwin            = (float*)(ws + o); o += (size_t)B_SZ * NWIN * DD * 4;
  unsigned short* statesb = (unsigned short*)(ws + o); o += (size_t)B_SZ * MAXST * HID * 2;
  unsigned short* W1f     = (unsigned short*)(ws + o); o += (size_t)W1FN * 2;
  unsigned short* W2f     = (unsigned short*)(ws + o); o += (size_t)WFN * 2;
  unsigned short* W3f     = (unsigned short*)(ws + o); o += (size_t)WFN * 2;
  unsigned short* Wlf     = (unsigned short*)(ws + o); o += (size_t)WFN * 2;

  SchedArgs P; CombArgs CB; ChainArgs CH; FuseArgs FU;
  build_sched(P, CB, CH, FU);

  prep_kernel<<<dim3(NWIN + 3, B_SZ), 128, 0, stream>>>(
      z, W1, W2, W3, Wl, logsig, dxwin, W1f, W2f, W3f, Wlf, P);
  comb_kernel<<<dim3(WIN, B_SZ), 128, 0, stream>>>(logsig, dxwin, CB);
  chain_kernel<<<32, 512, 0, stream>>>(logsig, W1f, W2f, W3f, b1, b2, b3, statesb, CH);
  fused_kernel<<<256, 256, 0, stream>>>(statesb, logsig, W1f, W2f, W3f, Wlf,
                                        b1, b2, b3, (float*)d_out, FU);
}

// Round 2
// 248.530 us; speedup vs baseline: 1.2504x; 1.2063x over previous
//
#include <hip/hip_runtime.h>
#include <hip/hip_bf16.h>
#include <cmath>
#include <cstring>

#define B_SZ   512
#define SLEN   1000
#define DD     16
#define HID    256
#define WIN    64
#define PAIRS  120
#define LSIG   136
#define NWIN   20
#define MAXST  21
#define K1P    416     // layer-1 K padded to x32
#define W1FN   (13 * 16 * 64 * 8)   // 106496 elems
#define WFN    (8 * 16 * 64 * 8)    // 65536 elems (W2/W3/Wl)
#define PSTEP  21      // partial buffer step slots (nsteps <= 20)

using short8 = __attribute__((ext_vector_type(8))) short;
using half8  = __attribute__((ext_vector_type(8))) _Float16;
using f32x4  = __attribute__((ext_vector_type(4))) float;

struct SchedArgs { short snapk[SLEN - 1]; };
struct CombArgs  { unsigned char winofm[WIN]; unsigned char zl[WIN]; };
struct ChainArgs { int nsteps; unsigned char kU[32]; };
struct FuseArgs  { unsigned char sidx[WIN]; };

__device__ __forceinline__ unsigned short f2h(float x) {
  _Float16 h = (_Float16)x;
  return __builtin_bit_cast(unsigned short, h);
}
__device__ __forceinline__ float ftanh(float x) {   // clamped; |err|~1e-6
  float t = fminf(fmaxf(2.f * x, -30.f), 30.f);
  float e = __expf(t);
  return (e - 1.f) / (e + 1.f);
}

// ---------------------------------------------------------------- prep: win scan + weight frag convert
// grid (NWIN+3, B_SZ) x 128. Blocks w<NWIN: per-window Levy scan. Else: convert
// W1/W2/W3/Wl -> fp16 MFMA B-frag layout:
//   Wf[(kk*16+nsub)*64+lane][j] = W[nsub*16+(lane&15)][kk*32+(lane>>4)*8+j]
__global__ __launch_bounds__(128) void prep_kernel(
    const float* __restrict__ z,
    const float* __restrict__ W1, const float* __restrict__ W2,
    const float* __restrict__ W3, const float* __restrict__ Wl,
    float* __restrict__ logsig, float* __restrict__ dxwin,
    unsigned short* __restrict__ W1f, unsigned short* __restrict__ W2f,
    unsigned short* __restrict__ W3f, unsigned short* __restrict__ Wlf,
    SchedArgs A)
{
  const int w = blockIdx.x, b = blockIdx.y, tid = threadIdx.x;
  if (w >= NWIN) {                                   // ---- weight conversion
    const int slot = ((w - NWIN) * B_SZ + b) * 128 + tid;   // 196608 slots
    for (int e = slot; e < W1FN + 3 * WFN; e += 3 * B_SZ * 128) {
      if (e < W1FN) {
        int f = e;
        int j = f & 7, l15 = (f >> 3) & 15, lq = (f >> 7) & 3, nsub = (f >> 9) & 15, kk = f >> 13;
        int row = nsub * 16 + l15, col = kk * 32 + lq * 8 + j;
        float v = (col < HID + LSIG) ? W1[(size_t)row * (HID + LSIG) + col] : 0.f;
        W1f[f] = f2h(v);
      } else {
        int e2 = e - W1FN;
        int which = e2 >> 16, f = e2 & 65535;
        int j = f & 7, l15 = (f >> 3) & 15, lq = (f >> 7) & 3, nsub = (f >> 9) & 15, kk = (f >> 13) & 7;
        int row = nsub * 16 + l15, col = kk * 32 + lq * 8 + j;
        const float* src = which == 0 ? W2 : which == 1 ? W3 : Wl;
        unsigned short* dst = which == 0 ? W2f : which == 1 ? W3f : Wlf;
        dst[f] = f2h(src[(size_t)row * HID + col]);
      }
    }
    return;
  }
  // ---- per-window Levy scan (dtsqrt inlined)
  __shared__ float zs[50][16];
  const int ns = (w == NWIN - 1) ? 49 : 50;
  const float* src = z + ((size_t)b * SLEN + 50 * w + 1) * DD;
  const double s999 = 1.0 / (double)(SLEN - 1);
  for (int c = tid; c < ns * 4; c += 128) {
    float4 v = ((const float4*)src)[c];
    int t = 50 * w + (c >> 2);
    double a = (t + 1 == SLEN - 1) ? 1.0 : (double)(t + 1) * s999;
    float s = sqrtf((float)(a - (double)t * s999));
    v.x *= s; v.y *= s; v.z *= s; v.w *= s;
    ((float4*)&zs[0][0])[c] = v;
  }
  int pi = 0, pj = 0;
  if (tid < PAIRS) { int rem = tid, i = 0; while (rem >= DD - 1 - i) { rem -= DD - 1 - i; ++i; } pi = i; pj = i + 1 + rem; }
  __syncthreads();
  float Yi = 0.f, Yj = 0.f, LL = 0.f, Yd = 0.f;
  const int base_t = 50 * w;
  for (int u = 0; u < ns; ++u) {
    const float di = zs[u][pi], dj = zs[u][pj];
    LL = fmaf(Yi, dj, LL); LL = fmaf(-Yj, di, LL);
    Yi += di; Yj += dj;
    if (tid < DD) Yd += zs[u][tid];
    const int m = A.snapk[base_t + u];
    if (m) {
      float* dst = logsig + ((size_t)b * WIN + m) * LSIG;
      if (tid < DD)    dst[tid]      = Yd;
      if (tid < PAIRS) dst[DD + tid] = LL;
    }
  }
  if (tid < DD) dxwin[((size_t)b * NWIN + w) * DD + tid] = Yd;
}

// ---------------------------------------------------------------- combine windows (fully parallel)
__global__ __launch_bounds__(128) void comb_kernel(
    float* __restrict__ logsig, const float* __restrict__ dxwin, CombArgs A)
{
  const int m = blockIdx.x, b = blockIdx.y, tid = threadIdx.x;
  float* row = logsig + ((size_t)b * WIN + m) * LSIG;
  if (m == 0) {
    if (tid < LSIG) row[tid] = 0.f;
    if (tid + 128 < LSIG) row[tid + 128] = 0.f;
    return;
  }
  __shared__ float Xs[DD], Yt[DD];
  const int w = A.winofm[m];
  if (tid < DD) {
    float acc = 0.f;
    for (int ww = 0; ww < w; ++ww) acc += dxwin[((size_t)b * NWIN + ww) * DD + tid];
    float y = row[tid];
    Xs[tid] = acc; Yt[tid] = y;
    row[tid] = acc + y;
  }
  __syncthreads();
  if (tid < PAIRS) {
    int rem = tid, i = 0; while (rem >= DD - 1 - i) { rem -= DD - 1 - i; ++i; }
    const int pi = i, pj = i + 1 + rem;
    float ll = row[DD + tid];
    row[DD + tid] = A.zl[m] ? 0.f : 0.5f * (ll + Xs[pi] * Yt[pj] - Xs[pj] * Yt[pi]);
  }
}

// ---------------------------------------------------------------- logsig partial precompute
// partial[g][m][col][row16] = (W1s . logsig[kU[m]])[row][col] + b1[col]  (f32,
// stored in the chain's C-fragment order so chain L1 inits acc with one
// float4/lane). Grid (32, nsteps) x 256 (4 waves x 64 cols). K=160 (5 ktiles,
// W1f kk=8..12; cols>=LSIG zero-padded on BOTH operands).
__global__ __launch_bounds__(256) void psig_kernel(
    const float* __restrict__ logsig, const unsigned short* __restrict__ W1f,
    const float* __restrict__ b1, float* __restrict__ partial, ChainArgs A)
{
  __shared__ __align__(16) unsigned short As[5 * 4 * 16 * 8];   // 5 KB
  const int g = blockIdx.x, m = blockIdx.y, tid = threadIdx.x;
  const int lane = tid & 63, w = tid >> 6;
  const int l15 = lane & 15, lq = lane >> 4;
  const int k = A.kU[m];
  for (int idx = tid; idx < 16 * 160; idx += 256) {
    int row = idx / 160, c = idx - row * 160;
    float v = (c < LSIG) ? logsig[(((size_t)(g * 16 + row)) * WIN + k) * LSIG + c] : 0.f;
    As[(((c >> 5) * 4 + ((c >> 3) & 3)) * 16 + row) * 8 + (c & 7)] = f2h(v);
  }
  __syncthreads();
  f32x4 acc[4] = {{0.f,0.f,0.f,0.f},{0.f,0.f,0.f,0.f},{0.f,0.f,0.f,0.f},{0.f,0.f,0.f,0.f}};
#pragma unroll
  for (int kt = 0; kt < 5; ++kt) {
    half8 af = *(const half8*)&As[((kt * 4 + lq) * 16 + l15) * 8];
#pragma unroll
    for (int t = 0; t < 4; ++t) {
      half8 bf = *(const half8*)(W1f + ((size_t)((8 + kt) * 16 + w * 4 + t) * 64 + lane) * 8);
      acc[t] = __builtin_amdgcn_mfma_f32_16x16x32_f16(af, bf, acc[t], 0, 0, 0);
    }
  }
#pragma unroll
  for (int t = 0; t < 4; ++t) {
    int col = w * 64 + t * 16 + l15;
    float bb = b1[col];
    f32x4 r = acc[t];
    r[0] += bb; r[1] += bb; r[2] += bb; r[3] += bb;
    *(f32x4*)&partial[(((size_t)g * PSTEP + m) * HID + col) * 16 + lq * 4] = r;
  }
}

// ---------------------------------------------------------------- sequential state chain (fp16 MFMA)
// 32 blocks x 512 thr (8 waves). M=16 rows/block; wave w owns cols [32w,32w+32).
// ALL weights (W1h/W2/W3 = 48 half8 frags = 192 regs) live in the unified
// VGPR/AGPR file (evidence r1: 128 arch + ~168 acc resident at 2 waves/SIMD
// with tiny FETCH). LDS is now only 3 x 8KB activation buffers -> per-step LDS
// traffic drops ~350KB -> ~220KB/CU. The logsig.W1s+b1 partial is precomputed
// by psig_kernel (f32, C-frag order): L1 = 16 MFMAs seeded from one float4
// prefetch/lane, issued one step ahead. Global state stores are deferred to
// the NEXT step's L1 region so the barrier vmcnt(0) drain is covered by
// compute instead of exposed at the L3 barrier. 3 barriers/step (minimum).
__global__ __attribute__((amdgpu_flat_work_group_size(512, 512)))
__attribute__((amdgpu_waves_per_eu(2, 2)))
void chain_kernel(
    const float* __restrict__ partial,
    const unsigned short* __restrict__ W1f, const unsigned short* __restrict__ W2f,
    const unsigned short* __restrict__ W3f,
    const float* __restrict__ b2, const float* __restrict__ b3,
    unsigned short* __restrict__ statesb, ChainArgs A)
{
  __shared__ __align__(16) unsigned short A0s[32 * 16 * 8];   // 8 KB (h, chunk-8)
  __shared__ __align__(16) unsigned short A1s[32 * 16 * 8];   // 8 KB
  __shared__ __align__(16) unsigned short A2s[32 * 16 * 8];   // 8 KB
  const int tid = threadIdx.x, g = blockIdx.x;
  const int lane = tid & 63, w = tid >> 6;
  const int l15 = lane & 15, lq = lane >> 4;

  for (int c = tid; c < 32 * 16 * 8; c += 512) A0s[c] = 0;
  for (int c = tid; c < 16 * HID; c += 512) {
    int r = c >> 8, col = c & 255;
    statesb[((size_t)(g * 16 + r) * MAXST + 0) * HID + col] = 0;
  }

  // ---- all weight frags -> registers (once, resident across all steps)
  half8 W1r[16], W2r[16], W3r[16];
#pragma unroll
  for (int kk = 0; kk < 8; ++kk)
#pragma unroll
    for (int nt = 0; nt < 2; ++nt) {
      W1r[kk * 2 + nt] = *(const half8*)(W1f + ((size_t)(kk * 16 + w * 2 + nt) * 64 + lane) * 8);
      W2r[kk * 2 + nt] = *(const half8*)(W2f + ((size_t)(kk * 16 + w * 2 + nt) * 64 + lane) * 8);
      W3r[kk * 2 + nt] = *(const half8*)(W3f + ((size_t)(kk * 16 + w * 2 + nt) * 64 + lane) * 8);
    }

  float bias2[2], bias3[2];
#pragma unroll
  for (int nt = 0; nt < 2; ++nt) {
    int col = (w * 2 + nt) * 16 + l15;
    bias2[nt] = b2[col]; bias3[nt] = b3[col];
  }

  // partial prefetch plumbing (per-lane float4 offsets, step 0 issued now)
  const float* pbase = partial + ((size_t)g * PSTEP) * HID * 16;
  int poff[2];
#pragma unroll
  for (int nt = 0; nt < 2; ++nt) {
    int col = w * 32 + nt * 16 + l15;
    poff[nt] = col * 16 + lq * 4;
  }
  f32x4 pf[2];
  pf[0] = *(const f32x4*)(pbase + poff[0]);
  pf[1] = *(const f32x4*)(pbase + poff[1]);

  unsigned short hv[2][4];                            // deferred state stores
  __syncthreads();                                    // A0s zeros visible

  for (int m = 0; m < A.nsteps; ++m) {
    if (m > 0) {                                      // store state m (from step m-1)
#pragma unroll
      for (int nt = 0; nt < 2; ++nt)
#pragma unroll
        for (int r4 = 0; r4 < 4; ++r4) {
          int row = lq * 4 + r4, col = w * 32 + nt * 16 + l15;
          statesb[((size_t)(g * 16 + row) * MAXST + m) * HID + col] = hv[nt][r4];
        }
    }
    // ---- L1: K=256 (h part), acc seeded from partial (has W1s.logsig + b1)
    {
      f32x4 acc[2][2];
      acc[0][0] = pf[0]; acc[0][1] = pf[1];
      acc[1][0] = (f32x4){0.f,0.f,0.f,0.f}; acc[1][1] = (f32x4){0.f,0.f,0.f,0.f};
      if (m + 1 < A.nsteps) {                         // prefetch next step's partial
        const float* pp = pbase + (size_t)(m + 1) * HID * 16;
        pf[0] = *(const f32x4*)(pp + poff[0]);
        pf[1] = *(const f32x4*)(pp + poff[1]);
      }
#pragma unroll
      for (int kk = 0; kk < 8; ++kk) {
        half8 af = *(const half8*)&A0s[((kk * 4 + lq) * 16 + l15) * 8];
        acc[kk & 1][0] = __builtin_amdgcn_mfma_f32_16x16x32_f16(af, W1r[kk * 2    ], acc[kk & 1][0], 0, 0, 0);
        acc[kk & 1][1] = __builtin_amdgcn_mfma_f32_16x16x32_f16(af, W1r[kk * 2 + 1], acc[kk & 1][1], 0, 0, 0);
      }
#pragma unroll
      for (int nt = 0; nt < 2; ++nt) {
        f32x4 s = acc[0][nt] + acc[1][nt];
        int col = w * 32 + nt * 16 + l15;
        int base = ((col >> 3) * 16) * 8 + (col & 7);
#pragma unroll
        for (int r4 = 0; r4 < 4; ++r4)
          A1s[base + (lq * 4 + r4) * 8] = f2h(fmaxf(s[r4], 0.f));
      }
    }
    __syncthreads();
    // ---- L2: K=256, W2 from registers
    {
      f32x4 acc[2][2] = {{{0.f,0.f,0.f,0.f},{0.f,0.f,0.f,0.f}},{{0.f,0.f,0.f,0.f},{0.f,0.f,0.f,0.f}}};
#pragma unroll
      for (int kk = 0; kk < 8; ++kk) {
        half8 af = *(const half8*)&A1s[((kk * 4 + lq) * 16 + l15) * 8];
        acc[kk & 1][0] = __builtin_amdgcn_mfma_f32_16x16x32_f16(af, W2r[kk * 2    ], acc[kk & 1][0], 0, 0, 0);
        acc[kk & 1][1] = __builtin_amdgcn_mfma_f32_16x16x32_f16(af, W2r[kk * 2 + 1], acc[kk & 1][1], 0, 0, 0);
      }
#pragma unroll
      for (int nt = 0; nt < 2; ++nt) {
        f32x4 s = acc[0][nt] + acc[1][nt];
        int col = w * 32 + nt * 16 + l15;
        int base = ((col >> 3) * 16) * 8 + (col & 7);
#pragma unroll
        for (int r4 = 0; r4 < 4; ++r4)
          A2s[base + (lq * 4 + r4) * 8] = f2h(fmaxf(s[r4] + bias2[nt], 0.f));
      }
    }
    __syncthreads();
    // ---- L3: K=256, W3 from registers; fast tanh -> A0 state; global store deferred
    {
      f32x4 acc[2][2] = {{{0.f,0.f,0.f,0.f},{0.f,0.f,0.f,0.f}},{{0.f,0.f,0.f,0.f},{0.f,0.f,0.f,0.f}}};
#pragma unroll
      for (int kk = 0; kk < 8; ++kk) {
        half8 af = *(const half8*)&A2s[((kk * 4 + lq) * 16 + l15) * 8];
        acc[kk & 1][0] = __builtin_amdgcn_mfma_f32_16x16x32_f16(af, W3r[kk * 2    ], acc[kk & 1][0], 0, 0, 0);
        acc[kk & 1][1] = __builtin_amdgcn_mfma_f32_16x16x32_f16(af, W3r[kk * 2 + 1], acc[kk & 1][1], 0, 0, 0);
      }
#pragma unroll
      for (int nt = 0; nt < 2; ++nt) {
        f32x4 s = acc[0][nt] + acc[1][nt];
        int col = w * 32 + nt * 16 + l15;
        int base = ((col >> 3) * 16) * 8 + (col & 7);
#pragma unroll
        for (int r4 = 0; r4 < 4; ++r4) {
          float tv = ftanh(s[r4] + bias3[nt]);
          unsigned short hvv = f2h(tv);
          hv[nt][r4] = hvv;
          A0s[base + (lq * 4 + r4) * 8] = hvv;
        }
      }
    }
    __syncthreads();
  }
  {                                                   // store final state (index nsteps)
    const int m = A.nsteps;
#pragma unroll
    for (int nt = 0; nt < 2; ++nt)
#pragma unroll
      for (int r4 = 0; r4 < 4; ++r4) {
        int row = lq * 4 + r4, col = w * 32 + nt * 16 + l15;
        statesb[((size_t)(g * 16 + row) * MAXST + m) * HID + col] = hv[nt][r4];
      }
  }
}

// ---------------------------------------------------------------- fused batched MLP (fp16 MFMA)
// 256 blocks x 256 thr (4 waves, 1 wave/SIMD -> full VGPR headroom). 128 rows
// (2 batch rows x 64 steps) x all 4 layers. Wave w owns n-tiles w*4..w*4+3
// (64 cols) x all 8 m-tiles -> acc[8][4], no duplicate B reads across waves.
// B-frags straight from L2 (pre-fragmented, 1KB/inst, each read once/block).
// Acts in chunk-of-8 LDS (conflict-free). Barriers: 13 (L1 A-staging, double-
// buffered) + 3 inter-layer  (was ~148).
__global__ __launch_bounds__(256, 1) void fused_kernel(
    const unsigned short* __restrict__ statesb, const float* __restrict__ logsig,
    const unsigned short* __restrict__ W1f, const unsigned short* __restrict__ W2f,
    const unsigned short* __restrict__ W3f, const unsigned short* __restrict__ Wlf,
    const float* __restrict__ b1, const float* __restrict__ b2, const float* __restrict__ b3,
    float* __restrict__ out, FuseArgs F)
{
  __shared__ __align__(16) unsigned short act1[32 * 128 * 8];   // 64 KB, chunk-8 [col>>3][row][col&7]
  __shared__ __align__(16) unsigned short act2[32 * 128 * 8];   // 64 KB
  __shared__ __align__(16) unsigned short atile[2][4 * 128 * 8];// 2 x 8 KB
  const int tid = threadIdx.x, band = blockIdx.x;
  const int lane = tid & 63, w = tid >> 6;
  const int l15 = lane & 15, lq = lane >> 4;

  float bias1[4], bias2[4], bias3[4];
#pragma unroll
  for (int t = 0; t < 4; ++t) {
    int col = w * 64 + t * 16 + l15;
    bias1[t] = b1[col]; bias2[t] = b2[col]; bias3[t] = b3[col];
  }

  // ---- L1: K=416, A staged per-kk (dbuf), B-frags from L2
  f32x4 acc[8][4];
#pragma unroll
  for (int a = 0; a < 8; ++a)
#pragma unroll
    for (int t = 0; t < 4; ++t) acc[a][t] = (f32x4){0.f, 0.f, 0.f, 0.f};

  short8 pk[2];
  auto loadA = [&](int kk, short8* p) {
#pragma unroll
    for (int i = 0; i < 2; ++i) {
      int c = tid + 256 * i;
      int r = c >> 2, cc = (c & 3) * 8;
      int col = kk * 32 + cc;
      int bA = band * 2 + (r >> 6), ks = r & 63;
      if (col < HID) {
        p[i] = *(const short8*)(statesb + ((size_t)bA * MAXST + F.sidx[ks]) * HID + col);
      } else {
        const float* sp = logsig + ((size_t)bA * WIN + ks) * LSIG + (col - HID); // tail reads past 136 benign (W pad=0)
        float4 v0 = ((const float4*)sp)[0];
        float4 v1 = ((const float4*)sp)[1];
        short8 q;
        q[0] = (short)f2h(v0.x); q[1] = (short)f2h(v0.y); q[2] = (short)f2h(v0.z); q[3] = (short)f2h(v0.w);
        q[4] = (short)f2h(v1.x); q[5] = (short)f2h(v1.y); q[6] = (short)f2h(v1.z); q[7] = (short)f2h(v1.w);
        p[i] = q;
      }
    }
  };
  loadA(0, pk);
  for (int kk = 0; kk < 13; ++kk) {
    unsigned short* buf = atile[kk & 1];
#pragma unroll
    for (int i = 0; i < 2; ++i) {
      int c = tid + 256 * i;
      int r = c >> 2, ch = c & 3;
      *(short8*)&buf[(ch * 128 + r) * 8] = pk[i];
    }
    __syncthreads();
    if (kk + 1 < 13) loadA(kk + 1, pk);       // issue early; hides under MFMAs
    half8 bfr[4];
#pragma unroll
    for (int t = 0; t < 4; ++t)
      bfr[t] = *(const half8*)(W1f + ((size_t)(kk * 16 + w * 4 + t) * 64 + lane) * 8);
#pragma unroll
    for (int a = 0; a < 8; ++a) {
      half8 af = *(const half8*)&buf[(lq * 128 + a * 16 + l15) * 8];
#pragma unroll
      for (int t = 0; t < 4; ++t)
        acc[a][t] = __builtin_amdgcn_mfma_f32_16x16x32_f16(af, bfr[t], acc[a][t], 0, 0, 0);
    }
    __syncthreads();
  }
#pragma unroll
  for (int a = 0; a < 8; ++a)
#pragma unroll
    for (int t = 0; t < 4; ++t) {
      int col = w * 64 + t * 16 + l15;
      int base = ((col >> 3) * 128) * 8 + (col & 7);
#pragma unroll
      for (int r4 = 0; r4 < 4; ++r4) {
        int row = a * 16 + lq * 4 + r4;
        act1[base + row * 8] = f2h(fmaxf(acc[a][t][r4] + bias1[t], 0.f));
      }
    }
  __syncthreads();

  // ---- generic K=256 layer: A from act LDS, B-frags from L2
  auto layer = [&](const unsigned short* inb, const unsigned short* Wf) {
#pragma unroll
    for (int a = 0; a < 8; ++a)
#pragma unroll
      for (int t = 0; t < 4; ++t) acc[a][t] = (f32x4){0.f, 0.f, 0.f, 0.f};
    for (int kk = 0; kk < 8; ++kk) {
      half8 bfr[4];
#pragma unroll
      for (int t = 0; t < 4; ++t)
        bfr[t] = *(const half8*)(Wf + ((size_t)(kk * 16 + w * 4 + t) * 64 + lane) * 8);
#pragma unroll
      for (int a = 0; a < 8; ++a) {
        half8 af = *(const half8*)&inb[((kk * 4 + lq) * 128 + a * 16 + l15) * 8];
#pragma unroll
        for (int t = 0; t < 4; ++t)
          acc[a][t] = __builtin_amdgcn_mfma_f32_16x16x32_f16(af, bfr[t], acc[a][t], 0, 0, 0);
      }
    }
  };

  layer(act1, W2f);                                   // L2 -> relu -> act2
#pragma unroll
  for (int a = 0; a < 8; ++a)
#pragma unroll
    for (int t = 0; t < 4; ++t) {
      int col = w * 64 + t * 16 + l15;
      int base = ((col >> 3) * 128) * 8 + (col & 7);
#pragma unroll
      for (int r4 = 0; r4 < 4; ++r4) {
        int row = a * 16 + lq * 4 + r4;
        act2[base + row * 8] = f2h(fmaxf(acc[a][t][r4] + bias2[t], 0.f));
      }
    }
  __syncthreads();

  layer(act2, W3f);                                   // L3 -> tanh -> act1
#pragma unroll
  for (int a = 0; a < 8; ++a)
#pragma unroll
    for (int t = 0; t < 4; ++t) {
      int col = w * 64 + t * 16 + l15;
      int base = ((col >> 3) * 128) * 8 + (col & 7);
#pragma unroll
      for (int r4 = 0; r4 < 4; ++r4) {
        int row = a * 16 + lq * 4 + r4;
        act1[base + row * 8] = f2h(ftanh(acc[a][t][r4] + bias3[t]));
      }
    }
  __syncthreads();

  layer(act1, Wlf);                                   // L4 -> fp32 out
#pragma unroll
  for (int a = 0; a < 8; ++a)
#pragma unroll
    for (int t = 0; t < 4; ++t) {
      int col = w * 64 + t * 16 + l15;
#pragma unroll
      for (int r4 = 0; r4 < 4; ++r4) {
        int row = a * 16 + lq * 4 + r4;
        out[((size_t)(band * 128 + row)) * HID + col] = acc[a][t][r4];
      }
    }
}

// ---------------------------------------------------------------- host schedule
static void build_sched(SchedArgs& P, CombArgs& CB, ChainArgs& CH, FuseArgs& FU) {
  double tb[SLEN], tt[WIN], tu[NWIN];
  const double s999 = 1.0 / (double)(SLEN - 1);
  const double s63  = 1.0 / (double)(WIN - 1);
  for (int i = 0; i < SLEN; ++i) tb[i] = (double)i * s999;
  tb[SLEN - 1] = 1.0;
  for (int k = 0; k < WIN; ++k) tt[k] = (double)k * s63;
  tt[WIN - 1] = 1.0;
  for (int j = 0; j < NWIN; ++j) tu[j] = tb[50 * j];

  int t_idx[WIN - 1], u_for_t[WIN - 1];
  for (int k = 1; k < WIN; ++k) {
    int ii = 0;
    for (int q = 0; q < SLEN; ++q) if (tb[q] <= tt[k]) ii = q;
    t_idx[k - 1] = ii;
    int jj = 0;
    for (int q = 0; q < NWIN; ++q) if (tu[q] <= tt[k]) jj = q;
    u_for_t[k - 1] = jj;
  }
  for (int t = 0; t < SLEN - 1; ++t) P.snapk[t] = 0;
  for (int m = 1; m < WIN; ++m) P.snapk[t_idx[m - 1] - 1] = (short)m;

  for (int m = 0; m < WIN; ++m) { CB.winofm[m] = 0; CB.zl[m] = 0; }
  for (int m = 1; m < WIN; ++m) {
    int p = t_idx[m - 1];
    CB.winofm[m] = (unsigned char)((p - 1) / 50);
    CB.zl[m] = (p % 50 == 0) ? 1 : 0;
  }

  double qt[32]; int nq = 0, last = -1;
  for (int m = 0; m < WIN - 1; ++m) {
    const int iu = u_for_t[m];
    if (iu != last) { qt[nq++] = tu[iu]; last = iu; }
  }
  qt[nq++] = tt[WIN - 1];
  int upd[WIN]; int qh = 0;
  for (int i = 0; i < WIN; ++i) {
    upd[i] = 0;
    if (qh < nq && tt[i] >= qt[qh]) { qh++; upd[i] = 1; }
  }
  int nU = 0;
  for (int k = 0; k < WIN; ++k) if (upd[k]) { if (nU < 32) CH.kU[nU] = (unsigned char)k; ++nU; }
  int cnt = 0;
  for (int k = 0; k < WIN; ++k) { FU.sidx[k] = (unsigned char)cnt; if (upd[k]) ++cnt; }
  CH.nsteps = FU.sidx[WIN - 1];
}

extern "C" void kernel_launch(void* const* d_in, const int* in_sizes, int n_in,
                              void* d_out, int out_size, void* d_ws, size_t ws_size,
                              hipStream_t stream) {
  const float* z  = (const float*)d_in[0];
  const float* W1 = (const float*)d_in[1];
  const float* b1 = (const float*)d_in[2];
  const float* W2 = (const float*)d_in[3];
  const float* b2 = (const float*)d_in[4];
  const float* W3 = (const float*)d_in[5];
  const float* b3 = (const float*)d_in[6];
  const float* Wl = (const float*)d_in[7];

  char* ws = (char*)d_ws;
  float* logsig = (float*)(ws);                                         // 17.83 MB
  size_t o = (size_t)B_SZ * WIN * LSIG * 4;
  float* dxwin            = (float*)(ws + o); o += (size_t)B_SZ * NWIN * DD * 4;
  unsigned short* statesb = (unsigned short*)(ws + o); o += (size_t)B_SZ * MAXST * HID * 2;
  unsigned short* W1f     = (unsigned short*)(ws + o); o += (size_t)W1FN * 2;
  unsigned short* W2f     = (unsigned short*)(ws + o); o += (size_t)WFN * 2;
  unsigned short* W3f     = (unsigned short*)(ws + o); o += (size_t)WFN * 2;
  unsigned short* Wlf     = (unsigned short*)(ws + o); o += (size_t)WFN * 2;
  float* partial          = (float*)(ws + o); o += (size_t)32 * PSTEP * HID * 16 * 4; // 11.0 MB

  SchedArgs P; CombArgs CB; ChainArgs CH; FuseArgs FU;
  build_sched(P, CB, CH, FU);

  prep_kernel<<<dim3(NWIN + 3, B_SZ), 128, 0, stream>>>(
      z, W1, W2, W3, Wl, logsig, dxwin, W1f, W2f, W3f, Wlf, P);
  comb_kernel<<<dim3(WIN, B_SZ), 128, 0, stream>>>(logsig, dxwin, CB);
  psig_kernel<<<dim3(32, CH.nsteps), 256, 0, stream>>>(logsig, W1f, b1, partial, CH);
  chain_kernel<<<32, 512, 0, stream>>>(partial, W1f, W2f, W3f, b2, b3, statesb, CH);
  fused_kernel<<<256, 256, 0, stream>>>(statesb, logsig, W1f, W2f, W3f, Wlf,
                                        b1, b2, b3, (float*)d_out, FU);
}

// Round 3
// 230.451 us; speedup vs baseline: 1.3485x; 1.0784x over previous
//
#include <hip/hip_runtime.h>
#include <hip/hip_bf16.h>
#include <cmath>
#include <cstring>

#define B_SZ   512
#define SLEN   1000
#define DD     16
#define HID    256
#define WIN    64
#define PAIRS  120
#define LSIG   136
#define NWIN   20
#define MAXST  21
#define K1P    416     // layer-1 K padded to x32
#define W1FN   (13 * 16 * 64 * 8)   // 106496 elems
#define WFN    (8 * 16 * 64 * 8)    // 65536 elems (W2/W3/Wl)
#define PSTEP  21      // partial buffer step slots (nsteps <= 20)

using short8  = __attribute__((ext_vector_type(8))) short;
using short4v = __attribute__((ext_vector_type(4))) short;
using half8   = __attribute__((ext_vector_type(8))) _Float16;
using f32x4   = __attribute__((ext_vector_type(4))) float;

struct SchedArgs { short snapk[SLEN - 1]; };
struct CombPArgs { unsigned char winofm[WIN]; unsigned char zl[WIN]; unsigned char sstep[WIN]; };
struct ChainArgs { int nsteps; unsigned char kU[32]; };
struct FuseArgs  { unsigned char sidx[WIN]; };

__device__ __forceinline__ unsigned short f2h(float x) {
  _Float16 h = (_Float16)x;
  return __builtin_bit_cast(unsigned short, h);
}
__device__ __forceinline__ float ftanh(float x) {   // clamped; |err|~1e-6
  float t = fminf(fmaxf(2.f * x, -30.f), 30.f);
  float e = __expf(t);
  return (e - 1.f) / (e + 1.f);
}

// ---------------------------------------------------------------- prep: win scan + weight frag convert
// grid (NWIN+3, B_SZ) x 128. Blocks w<NWIN: per-window Levy scan. Else: convert
// W1/W2/W3/Wl -> fp16 MFMA B-frag layout:
//   Wf[(kk*16+nsub)*64+lane][j] = W[nsub*16+(lane&15)][kk*32+(lane>>4)*8+j]
__global__ __launch_bounds__(128) void prep_kernel(
    const float* __restrict__ z,
    const float* __restrict__ W1, const float* __restrict__ W2,
    const float* __restrict__ W3, const float* __restrict__ Wl,
    float* __restrict__ logsig, float* __restrict__ dxwin,
    unsigned short* __restrict__ W1f, unsigned short* __restrict__ W2f,
    unsigned short* __restrict__ W3f, unsigned short* __restrict__ Wlf,
    SchedArgs A)
{
  const int w = blockIdx.x, b = blockIdx.y, tid = threadIdx.x;
  if (w >= NWIN) {                                   // ---- weight conversion
    const int slot = ((w - NWIN) * B_SZ + b) * 128 + tid;   // 196608 slots
    for (int e = slot; e < W1FN + 3 * WFN; e += 3 * B_SZ * 128) {
      if (e < W1FN) {
        int f = e;
        int j = f & 7, l15 = (f >> 3) & 15, lq = (f >> 7) & 3, nsub = (f >> 9) & 15, kk = f >> 13;
        int row = nsub * 16 + l15, col = kk * 32 + lq * 8 + j;
        float v = (col < HID + LSIG) ? W1[(size_t)row * (HID + LSIG) + col] : 0.f;
        W1f[f] = f2h(v);
      } else {
        int e2 = e - W1FN;
        int which = e2 >> 16, f = e2 & 65535;
        int j = f & 7, l15 = (f >> 3) & 15, lq = (f >> 7) & 3, nsub = (f >> 9) & 15, kk = (f >> 13) & 7;
        int row = nsub * 16 + l15, col = kk * 32 + lq * 8 + j;
        const float* src = which == 0 ? W2 : which == 1 ? W3 : Wl;
        unsigned short* dst = which == 0 ? W2f : which == 1 ? W3f : Wlf;
        dst[f] = f2h(src[(size_t)row * HID + col]);
      }
    }
    return;
  }
  // ---- per-window Levy scan (dtsqrt inlined)
  __shared__ float zs[50][16];
  const int ns = (w == NWIN - 1) ? 49 : 50;
  const float* src = z + ((size_t)b * SLEN + 50 * w + 1) * DD;
  const double s999 = 1.0 / (double)(SLEN - 1);
  for (int c = tid; c < ns * 4; c += 128) {
    float4 v = ((const float4*)src)[c];
    int t = 50 * w + (c >> 2);
    double a = (t + 1 == SLEN - 1) ? 1.0 : (double)(t + 1) * s999;
    float s = sqrtf((float)(a - (double)t * s999));
    v.x *= s; v.y *= s; v.z *= s; v.w *= s;
    ((float4*)&zs[0][0])[c] = v;
  }
  int pi = 0, pj = 0;
  if (tid < PAIRS) { int rem = tid, i = 0; while (rem >= DD - 1 - i) { rem -= DD - 1 - i; ++i; } pi = i; pj = i + 1 + rem; }
  __syncthreads();
  float Yi = 0.f, Yj = 0.f, LL = 0.f, Yd = 0.f;
  const int base_t = 50 * w;
  for (int u = 0; u < ns; ++u) {
    const float di = zs[u][pi], dj = zs[u][pj];
    LL = fmaf(Yi, dj, LL); LL = fmaf(-Yj, di, LL);
    Yi += di; Yj += dj;
    if (tid < DD) Yd += zs[u][tid];
    const int m = A.snapk[base_t + u];
    if (m) {
      float* dst = logsig + ((size_t)b * WIN + m) * LSIG;
      if (tid < DD)    dst[tid]      = Yd;
      if (tid < PAIRS) dst[DD + tid] = LL;
    }
  }
  if (tid < DD) dxwin[((size_t)b * NWIN + w) * DD + tid] = Yd;
}

// ---------------------------------------------------------------- combine + logsig partial (merged)
// grid (WIN, 32) x 256. Block (k, g): finalize logsig rows for 16 batches
// (b = 16g..16g+15) at window k (level-1 add + Levy adjust), then -- if k is
// an update step (sstep[k]!=255) -- compute the chain's L1 partial
// partial[g][s][row][col] = (W1s . logsig)[row][col] + b1[col] straight from
// LDS with swapped-operand MFMA (D[feature][batch]: lane&15 = batch row, each
// lane holds 4 consecutive out-cols -> row-major float4 store). Replaces the
// old comb_kernel + psig_kernel pair (one fewer dispatch, no logsig re-read).
__global__ __launch_bounds__(256) void combp_kernel(
    float* __restrict__ logsig, const float* __restrict__ dxwin,
    const unsigned short* __restrict__ W1f, const float* __restrict__ b1,
    float* __restrict__ partial, CombPArgs A)
{
  __shared__ float Xs[16][16], Yt[16][16];
  __shared__ __align__(16) unsigned short As[20 * 16 * 8];   // 160 cols, chunk-8
  const int k = blockIdx.x, g = blockIdx.y, tid = threadIdx.x;
  const int w = A.winofm[k], zl = A.zl[k], ss = A.sstep[k];
  for (int c = tid; c < 3 * 16 * 8; c += 256) As[17 * 16 * 8 + c] = 0;  // zero pad cols 136..159
  {                                                   // ---- level-1 (tid = bi*16+col)
    const int bi = tid >> 4, col = tid & 15;
    const size_t b = (size_t)(g * 16 + bi);
    float acc = 0.f;
    for (int ww = 0; ww < w; ++ww) acc += dxwin[(b * NWIN + ww) * DD + col];
    float y = (k == 0) ? 0.f : logsig[(b * WIN + k) * LSIG + col];
    float fin = (k == 0) ? 0.f : acc + y;
    Xs[bi][col] = acc; Yt[bi][col] = y;
    logsig[(b * WIN + k) * LSIG + col] = fin;
    As[((col >> 3) * 16 + bi) * 8 + (col & 7)] = f2h(fin);
  }
  __syncthreads();
  for (int idx = tid; idx < 16 * PAIRS; idx += 256) {  // ---- Levy pairs
    const int bi = idx / PAIRS, p = idx - bi * PAIRS;
    int rem = p, i = 0; while (rem >= DD - 1 - i) { rem -= DD - 1 - i; ++i; }
    const int pi = i, pj = i + 1 + rem;
    const size_t b = (size_t)(g * 16 + bi);
    float ll = (k == 0) ? 0.f : logsig[(b * WIN + k) * LSIG + DD + p];
    float fin = (k == 0 || zl) ? 0.f
              : 0.5f * (ll + Xs[bi][pi] * Yt[bi][pj] - Xs[bi][pj] * Yt[bi][pi]);
    logsig[(b * WIN + k) * LSIG + DD + p] = fin;
    const int c = DD + p;
    As[((c >> 3) * 16 + bi) * 8 + (c & 7)] = f2h(fin);
  }
  if (ss == 255) return;                               // uniform across block
  __syncthreads();
  const int lane = tid & 63, wv = tid >> 6;
  const int l15 = lane & 15, lq = lane >> 4;
  f32x4 acc4[4] = {{0,0,0,0},{0,0,0,0},{0,0,0,0},{0,0,0,0}};
#pragma unroll
  for (int kt = 0; kt < 5; ++kt) {
    half8 af = *(const half8*)&As[((kt * 4 + lq) * 16 + l15) * 8];
#pragma unroll
    for (int t = 0; t < 4; ++t) {
      half8 bfW = *(const half8*)(W1f + ((size_t)((8 + kt) * 16 + wv * 4 + t) * 64 + lane) * 8);
      acc4[t] = __builtin_amdgcn_mfma_f32_16x16x32_f16(bfW, af, acc4[t], 0, 0, 0);
    }
  }
#pragma unroll
  for (int t = 0; t < 4; ++t) {
    const int col0 = wv * 64 + t * 16 + lq * 4;
    f32x4 bb = *(const f32x4*)(b1 + col0);
    f32x4 r = acc4[t] + bb;
    *(f32x4*)&partial[(((size_t)g * PSTEP + ss) * 16 + l15) * HID + col0] = r;
  }
}

// ---------------------------------------------------------------- sequential state chain (fp16 MFMA)
// 32 blocks x 512 thr (8 waves). M=16 rows/block; wave w owns cols [32w,32w+32).
// All weights (48 half8 frags) resident in the unified VGPR/AGPR file
// (r1/r2 evidence: tiny FETCH). SWAPPED-OPERAND MFMA: D[feature][batch], so
// lane&15 = batch row and each lane holds 4 CONSECUTIVE out-cols -> epilogue
// is 2x ds_write_b64 per wave per layer (was 8x ds_write_b16) and state
// export is a packed 8B global store. LDS-pipe instr count per layer drops
// 128->80 per CU; that pipe was the per-step critical path. 3 barriers/step.
__global__ __attribute__((amdgpu_flat_work_group_size(512, 512)))
__attribute__((amdgpu_waves_per_eu(2, 2)))
void chain_kernel(
    const float* __restrict__ partial,
    const unsigned short* __restrict__ W1f, const unsigned short* __restrict__ W2f,
    const unsigned short* __restrict__ W3f,
    const float* __restrict__ b2, const float* __restrict__ b3,
    unsigned short* __restrict__ statesb, ChainArgs A)
{
  __shared__ __align__(16) unsigned short A0s[32 * 16 * 8];   // 8 KB (h, chunk-8)
  __shared__ __align__(16) unsigned short A1s[32 * 16 * 8];   // 8 KB
  __shared__ __align__(16) unsigned short A2s[32 * 16 * 8];   // 8 KB
  const int tid = threadIdx.x, g = blockIdx.x;
  const int lane = tid & 63, w = tid >> 6;
  const int l15 = lane & 15, lq = lane >> 4;

  for (int c = tid; c < 32 * 16 * 8; c += 512) A0s[c] = 0;
  for (int c = tid; c < 16 * HID; c += 512) {
    int r = c >> 8, col = c & 255;
    statesb[((size_t)(g * 16 + r) * MAXST + 0) * HID + col] = 0;
  }

  // ---- all weight frags -> registers (once, resident across all steps)
  half8 W1r[16], W2r[16], W3r[16];
#pragma unroll
  for (int kk = 0; kk < 8; ++kk)
#pragma unroll
    for (int nt = 0; nt < 2; ++nt) {
      W1r[kk * 2 + nt] = *(const half8*)(W1f + ((size_t)(kk * 16 + w * 2 + nt) * 64 + lane) * 8);
      W2r[kk * 2 + nt] = *(const half8*)(W2f + ((size_t)(kk * 16 + w * 2 + nt) * 64 + lane) * 8);
      W3r[kk * 2 + nt] = *(const half8*)(W3f + ((size_t)(kk * 16 + w * 2 + nt) * 64 + lane) * 8);
    }

  // per-lane column base (4 consecutive cols) for each n-tile
  int colb[2];
  f32x4 bias2v[2], bias3v[2];
#pragma unroll
  for (int nt = 0; nt < 2; ++nt) {
    colb[nt] = w * 32 + nt * 16 + lq * 4;
    bias2v[nt] = *(const f32x4*)(b2 + colb[nt]);
    bias3v[nt] = *(const f32x4*)(b3 + colb[nt]);
  }

  // partial prefetch plumbing (row-major [step][row16][256], float4/lane)
  const float* pbase = partial + (size_t)g * PSTEP * 16 * HID;
  int poff[2];
#pragma unroll
  for (int nt = 0; nt < 2; ++nt) poff[nt] = l15 * HID + colb[nt];
  f32x4 pf[2];
  pf[0] = *(const f32x4*)(pbase + poff[0]);
  pf[1] = *(const f32x4*)(pbase + poff[1]);

  short4v hv4[2];                                     // deferred packed state stores
  __syncthreads();                                    // A0s zeros visible

  for (int m = 0; m < A.nsteps; ++m) {
    if (m > 0) {                                      // store state m (from step m-1), 8B packed
#pragma unroll
      for (int nt = 0; nt < 2; ++nt)
        *(short4v*)&statesb[((size_t)(g * 16 + l15) * MAXST + m) * HID + colb[nt]] = hv4[nt];
    }
    // ---- L1: K=256 (h part), acc seeded from partial (has W1s.logsig + b1)
    {
      f32x4 acc[2][2];
      acc[0][0] = pf[0]; acc[0][1] = pf[1];
      acc[1][0] = (f32x4){0.f,0.f,0.f,0.f}; acc[1][1] = (f32x4){0.f,0.f,0.f,0.f};
      if (m + 1 < A.nsteps) {                         // prefetch next step's partial
        const float* pp = pbase + (size_t)(m + 1) * 16 * HID;
        pf[0] = *(const f32x4*)(pp + poff[0]);
        pf[1] = *(const f32x4*)(pp + poff[1]);
      }
#pragma unroll
      for (int kk = 0; kk < 8; ++kk) {
        half8 af = *(const half8*)&A0s[((kk * 4 + lq) * 16 + l15) * 8];
        acc[kk & 1][0] = __builtin_amdgcn_mfma_f32_16x16x32_f16(W1r[kk * 2    ], af, acc[kk & 1][0], 0, 0, 0);
        acc[kk & 1][1] = __builtin_amdgcn_mfma_f32_16x16x32_f16(W1r[kk * 2 + 1], af, acc[kk & 1][1], 0, 0, 0);
      }
#pragma unroll
      for (int nt = 0; nt < 2; ++nt) {
        f32x4 s = acc[0][nt] + acc[1][nt];
        short4v h4;
#pragma unroll
        for (int r4 = 0; r4 < 4; ++r4) h4[r4] = (short)f2h(fmaxf(s[r4], 0.f));
        *(short4v*)&A1s[((colb[nt] >> 3) * 16 + l15) * 8 + (colb[nt] & 7)] = h4;
      }
    }
    __syncthreads();
    // ---- L2: K=256, W2 from registers
    {
      f32x4 acc[2][2] = {{{0.f,0.f,0.f,0.f},{0.f,0.f,0.f,0.f}},{{0.f,0.f,0.f,0.f},{0.f,0.f,0.f,0.f}}};
#pragma unroll
      for (int kk = 0; kk < 8; ++kk) {
        half8 af = *(const half8*)&A1s[((kk * 4 + lq) * 16 + l15) * 8];
        acc[kk & 1][0] = __builtin_amdgcn_mfma_f32_16x16x32_f16(W2r[kk * 2    ], af, acc[kk & 1][0], 0, 0, 0);
        acc[kk & 1][1] = __builtin_amdgcn_mfma_f32_16x16x32_f16(W2r[kk * 2 + 1], af, acc[kk & 1][1], 0, 0, 0);
      }
#pragma unroll
      for (int nt = 0; nt < 2; ++nt) {
        f32x4 s = acc[0][nt] + acc[1][nt] + bias2v[nt];
        short4v h4;
#pragma unroll
        for (int r4 = 0; r4 < 4; ++r4) h4[r4] = (short)f2h(fmaxf(s[r4], 0.f));
        *(short4v*)&A2s[((colb[nt] >> 3) * 16 + l15) * 8 + (colb[nt] & 7)] = h4;
      }
    }
    __syncthreads();
    // ---- L3: K=256, W3 from registers; fast tanh -> A0 state; global store deferred
    {
      f32x4 acc[2][2] = {{{0.f,0.f,0.f,0.f},{0.f,0.f,0.f,0.f}},{{0.f,0.f,0.f,0.f},{0.f,0.f,0.f,0.f}}};
#pragma unroll
      for (int kk = 0; kk < 8; ++kk) {
        half8 af = *(const half8*)&A2s[((kk * 4 + lq) * 16 + l15) * 8];
        acc[kk & 1][0] = __builtin_amdgcn_mfma_f32_16x16x32_f16(W3r[kk * 2    ], af, acc[kk & 1][0], 0, 0, 0);
        acc[kk & 1][1] = __builtin_amdgcn_mfma_f32_16x16x32_f16(W3r[kk * 2 + 1], af, acc[kk & 1][1], 0, 0, 0);
      }
#pragma unroll
      for (int nt = 0; nt < 2; ++nt) {
        f32x4 s = acc[0][nt] + acc[1][nt] + bias3v[nt];
        short4v h4;
#pragma unroll
        for (int r4 = 0; r4 < 4; ++r4) h4[r4] = (short)f2h(ftanh(s[r4]));
        hv4[nt] = h4;
        *(short4v*)&A0s[((colb[nt] >> 3) * 16 + l15) * 8 + (colb[nt] & 7)] = h4;
      }
    }
    __syncthreads();
  }
  {                                                   // store final state (index nsteps)
    const int m = A.nsteps;
#pragma unroll
    for (int nt = 0; nt < 2; ++nt)
      *(short4v*)&statesb[((size_t)(g * 16 + l15) * MAXST + m) * HID + colb[nt]] = hv4[nt];
  }
}

// ---------------------------------------------------------------- fused batched MLP (fp16 MFMA)
// 256 blocks x 256 thr (4 waves, 1 wave/SIMD). 128 rows x 4 layers, wave w
// owns 64 cols x all 8 m-tiles -> acc[8][4]. SWAPPED-OPERAND MFMA: epilogues
// are packed ds_write_b64 (was 4x b16) and the final out store is a
// global_store_dwordx4 float4 (was 4 scattered dwords). L1 A-staging now
// single-barrier double-buffered (13 barriers, was 26; skew bounded by 1
// barrier -> alternate buffers never collide).
__global__ __launch_bounds__(256, 1) void fused_kernel(
    const unsigned short* __restrict__ statesb, const float* __restrict__ logsig,
    const unsigned short* __restrict__ W1f, const unsigned short* __restrict__ W2f,
    const unsigned short* __restrict__ W3f, const unsigned short* __restrict__ Wlf,
    const float* __restrict__ b1, const float* __restrict__ b2, const float* __restrict__ b3,
    float* __restrict__ out, FuseArgs F)
{
  __shared__ __align__(16) unsigned short act1[32 * 128 * 8];   // 64 KB, chunk-8 [col>>3][row][col&7]
  __shared__ __align__(16) unsigned short act2[32 * 128 * 8];   // 64 KB
  __shared__ __align__(16) unsigned short atile[2][4 * 128 * 8];// 2 x 8 KB
  const int tid = threadIdx.x, band = blockIdx.x;
  const int lane = tid & 63, w = tid >> 6;
  const int l15 = lane & 15, lq = lane >> 4;

  // ---- L1: K=416, A staged per-kk (dbuf, 1 barrier/kk), B-frags from L2
  f32x4 acc[8][4];
#pragma unroll
  for (int a = 0; a < 8; ++a)
#pragma unroll
    for (int t = 0; t < 4; ++t) acc[a][t] = (f32x4){0.f, 0.f, 0.f, 0.f};

  short8 pk[2];
  auto loadA = [&](int kk, short8* p) {
#pragma unroll
    for (int i = 0; i < 2; ++i) {
      int c = tid + 256 * i;
      int r = c >> 2, cc = (c & 3) * 8;
      int col = kk * 32 + cc;
      int bA = band * 2 + (r >> 6), ks = r & 63;
      if (col < HID) {
        p[i] = *(const short8*)(statesb + ((size_t)bA * MAXST + F.sidx[ks]) * HID + col);
      } else {
        const float* sp = logsig + ((size_t)bA * WIN + ks) * LSIG + (col - HID); // tail reads past 136 benign (W pad=0)
        float4 v0 = ((const float4*)sp)[0];
        float4 v1 = ((const float4*)sp)[1];
        short8 q;
        q[0] = (short)f2h(v0.x); q[1] = (short)f2h(v0.y); q[2] = (short)f2h(v0.z); q[3] = (short)f2h(v0.w);
        q[4] = (short)f2h(v1.x); q[5] = (short)f2h(v1.y); q[6] = (short)f2h(v1.z); q[7] = (short)f2h(v1.w);
        p[i] = q;
      }
    }
  };
  loadA(0, pk);
  for (int kk = 0; kk < 13; ++kk) {
    unsigned short* buf = &atile[kk & 1][0];
#pragma unroll
    for (int i = 0; i < 2; ++i) {
      int c = tid + 256 * i;
      int r = c >> 2, ch = c & 3;
      *(short8*)&buf[(ch * 128 + r) * 8] = pk[i];
    }
    __syncthreads();
    if (kk + 1 < 13) loadA(kk + 1, pk);       // issue early; hides under MFMAs
    half8 bfr[4];
#pragma unroll
    for (int t = 0; t < 4; ++t)
      bfr[t] = *(const half8*)(W1f + ((size_t)(kk * 16 + w * 4 + t) * 64 + lane) * 8);
#pragma unroll
    for (int a = 0; a < 8; ++a) {
      half8 af = *(const half8*)&buf[(lq * 128 + a * 16 + l15) * 8];
#pragma unroll
      for (int t = 0; t < 4; ++t)
        acc[a][t] = __builtin_amdgcn_mfma_f32_16x16x32_f16(bfr[t], af, acc[a][t], 0, 0, 0);
    }
  }
#pragma unroll
  for (int t = 0; t < 4; ++t) {
    const int col0 = w * 64 + t * 16 + lq * 4;
    f32x4 bb = *(const f32x4*)(b1 + col0);
#pragma unroll
    for (int a = 0; a < 8; ++a) {
      const int row = a * 16 + l15;
      short4v h4;
#pragma unroll
      for (int r4 = 0; r4 < 4; ++r4) h4[r4] = (short)f2h(fmaxf(acc[a][t][r4] + bb[r4], 0.f));
      *(short4v*)&act1[((col0 >> 3) * 128 + row) * 8 + (col0 & 7)] = h4;
    }
  }
  __syncthreads();

  // ---- generic K=256 layer: A from act LDS, W-frags (A-operand) from L2
  auto layer = [&](const unsigned short* inb, const unsigned short* Wf) {
#pragma unroll
    for (int a = 0; a < 8; ++a)
#pragma unroll
      for (int t = 0; t < 4; ++t) acc[a][t] = (f32x4){0.f, 0.f, 0.f, 0.f};
    for (int kk = 0; kk < 8; ++kk) {
      half8 bfr[4];
#pragma unroll
      for (int t = 0; t < 4; ++t)
        bfr[t] = *(const half8*)(Wf + ((size_t)(kk * 16 + w * 4 + t) * 64 + lane) * 8);
#pragma unroll
      for (int a = 0; a < 8; ++a) {
        half8 af = *(const half8*)&inb[((kk * 4 + lq) * 128 + a * 16 + l15) * 8];
#pragma unroll
        for (int t = 0; t < 4; ++t)
          acc[a][t] = __builtin_amdgcn_mfma_f32_16x16x32_f16(bfr[t], af, acc[a][t], 0, 0, 0);
      }
    }
  };

  layer(act1, W2f);                                   // L2 -> relu -> act2
#pragma unroll
  for (int t = 0; t < 4; ++t) {
    const int col0 = w * 64 + t * 16 + lq * 4;
    f32x4 bb = *(const f32x4*)(b2 + col0);
#pragma unroll
    for (int a = 0; a < 8; ++a) {
      const int row = a * 16 + l15;
      short4v h4;
#pragma unroll
      for (int r4 = 0; r4 < 4; ++r4) h4[r4] = (short)f2h(fmaxf(acc[a][t][r4] + bb[r4], 0.f));
      *(short4v*)&act2[((col0 >> 3) * 128 + row) * 8 + (col0 & 7)] = h4;
    }
  }
  __syncthreads();

  layer(act2, W3f);                                   // L3 -> tanh -> act1
#pragma unroll
  for (int t = 0; t < 4; ++t) {
    const int col0 = w * 64 + t * 16 + lq * 4;
    f32x4 bb = *(const f32x4*)(b3 + col0);
#pragma unroll
    for (int a = 0; a < 8; ++a) {
      const int row = a * 16 + l15;
      short4v h4;
#pragma unroll
      for (int r4 = 0; r4 < 4; ++r4) h4[r4] = (short)f2h(ftanh(acc[a][t][r4] + bb[r4]));
      *(short4v*)&act1[((col0 >> 3) * 128 + row) * 8 + (col0 & 7)] = h4;
    }
  }
  __syncthreads();

  layer(act1, Wlf);                                   // L4 -> fp32 out (float4 stores)
#pragma unroll
  for (int t = 0; t < 4; ++t) {
    const int col0 = w * 64 + t * 16 + lq * 4;
#pragma unroll
    for (int a = 0; a < 8; ++a) {
      const int row = a * 16 + l15;
      *(f32x4*)&out[((size_t)(band * 128 + row)) * HID + col0] = acc[a][t];
    }
  }
}

// ---------------------------------------------------------------- host schedule
static void build_sched(SchedArgs& P, CombPArgs& CB, ChainArgs& CH, FuseArgs& FU) {
  double tb[SLEN], tt[WIN], tu[NWIN];
  const double s999 = 1.0 / (double)(SLEN - 1);
  const double s63  = 1.0 / (double)(WIN - 1);
  for (int i = 0; i < SLEN; ++i) tb[i] = (double)i * s999;
  tb[SLEN - 1] = 1.0;
  for (int k = 0; k < WIN; ++k) tt[k] = (double)k * s63;
  tt[WIN - 1] = 1.0;
  for (int j = 0; j < NWIN; ++j) tu[j] = tb[50 * j];

  int t_idx[WIN - 1], u_for_t[WIN - 1];
  for (int k = 1; k < WIN; ++k) {
    int ii = 0;
    for (int q = 0; q < SLEN; ++q) if (tb[q] <= tt[k]) ii = q;
    t_idx[k - 1] = ii;
    int jj = 0;
    for (int q = 0; q < NWIN; ++q) if (tu[q] <= tt[k]) jj = q;
    u_for_t[k - 1] = jj;
  }
  for (int t = 0; t < SLEN - 1; ++t) P.snapk[t] = 0;
  for (int m = 1; m < WIN; ++m) P.snapk[t_idx[m - 1] - 1] = (short)m;

  for (int m = 0; m < WIN; ++m) { CB.winofm[m] = 0; CB.zl[m] = 0; CB.sstep[m] = 255; }
  for (int m = 1; m < WIN; ++m) {
    int p = t_idx[m - 1];
    CB.winofm[m] = (unsigned char)((p - 1) / 50);
    CB.zl[m] = (p % 50 == 0) ? 1 : 0;
  }

  double qt[32]; int nq = 0, last = -1;
  for (int m = 0; m < WIN - 1; ++m) {
    const int iu = u_for_t[m];
    if (iu != last) { qt[nq++] = tu[iu]; last = iu; }
  }
  qt[nq++] = tt[WIN - 1];
  int upd[WIN]; int qh = 0;
  for (int i = 0; i < WIN; ++i) {
    upd[i] = 0;
    if (qh < nq && tt[i] >= qt[qh]) { qh++; upd[i] = 1; }
  }
  int nU = 0;
  for (int k = 0; k < WIN; ++k) if (upd[k]) { if (nU < 32) CH.kU[nU] = (unsigned char)k; ++nU; }
  int cnt = 0;
  for (int k = 0; k < WIN; ++k) { FU.sidx[k] = (unsigned char)cnt; if (upd[k]) ++cnt; }
  CH.nsteps = FU.sidx[WIN - 1];
  for (int s = 0; s < nU && s < 32; ++s)
    if (s < PSTEP) CB.sstep[CH.kU[s]] = (unsigned char)s;
}

extern "C" void kernel_launch(void* const* d_in, const int* in_sizes, int n_in,
                              void* d_out, int out_size, void* d_ws, size_t ws_size,
                              hipStream_t stream) {
  const float* z  = (const float*)d_in[0];
  const float* W1 = (const float*)d_in[1];
  const float* b1 = (const float*)d_in[2];
  const float* W2 = (const float*)d_in[3];
  const float* b2 = (const float*)d_in[4];
  const float* W3 = (const float*)d_in[5];
  const float* b3 = (const float*)d_in[6];
  const float* Wl = (const float*)d_in[7];

  char* ws = (char*)d_ws;
  float* logsig = (float*)(ws);                                         // 17.83 MB
  size_t o = (size_t)B_SZ * WIN * LSIG * 4;
  float* dxwin            = (float*)(ws + o); o += (size_t)B_SZ * NWIN * DD * 4;
  unsigned short* statesb = (unsigned short*)(ws + o); o += (size_t)B_SZ * MAXST * HID * 2;
  unsigned short* W1f     = (unsigned short*)(ws + o); o += (size_t)W1FN * 2;
  unsigned short* W2f     = (unsigned short*)(ws + o); o += (size_t)WFN * 2;
  unsigned short* W3f     = (unsigned short*)(ws + o); o += (size_t)WFN * 2;
  unsigned short* Wlf     = (unsigned short*)(ws + o); o += (size_t)WFN * 2;
  float* partial          = (float*)(ws + o); o += (size_t)32 * PSTEP * 16 * HID * 4; // 11.0 MB

  SchedArgs P; CombPArgs CB; ChainArgs CH; FuseArgs FU;
  build_sched(P, CB, CH, FU);

  prep_kernel<<<dim3(NWIN + 3, B_SZ), 128, 0, stream>>>(
      z, W1, W2, W3, Wl, logsig, dxwin, W1f, W2f, W3f, Wlf, P);
  combp_kernel<<<dim3(WIN, 32), 256, 0, stream>>>(logsig, dxwin, W1f, b1, partial, CB);
  chain_kernel<<<32, 512, 0, stream>>>(partial, W1f, W2f, W3f, b2, b3, statesb, CH);
  fused_kernel<<<256, 256, 0, stream>>>(statesb, logsig, W1f, W2f, W3f, Wlf,
                                        b1, b2, b3, (float*)d_out, FU);
}

// Round 4
// 217.957 us; speedup vs baseline: 1.4258x; 1.0573x over previous
//
#include <hip/hip_runtime.h>
#include <hip/hip_bf16.h>
#include <cmath>
#include <cstring>

#define B_SZ   512
#define SLEN   1000
#define DD     16
#define HID    256
#define WIN    64
#define PAIRS  120
#define LSIG   136
#define NWIN   20
#define MAXST  21
#define K1P    416     // layer-1 K padded to x32
#define W1FN   (13 * 16 * 64 * 8)   // 106496 elems
#define WFN    (8 * 16 * 64 * 8)    // 65536 elems (W2/W3/Wl)
#define PSTEP  21      // partial buffer step slots (nsteps <= 20)

using short8  = __attribute__((ext_vector_type(8))) short;
using short4v = __attribute__((ext_vector_type(4))) short;
using half8   = __attribute__((ext_vector_type(8))) _Float16;
using f32x4   = __attribute__((ext_vector_type(4))) float;

struct SchedArgs { short snapk[SLEN - 1]; };
struct CombPArgs { unsigned char winofm[WIN]; unsigned char zl[WIN]; unsigned char sstep[WIN]; };
struct ChainArgs { int nsteps; unsigned char kU[32]; };
struct FuseArgs  { unsigned char sidx[WIN]; };

__device__ __forceinline__ unsigned short f2h(float x) {
  _Float16 h = (_Float16)x;
  return __builtin_bit_cast(unsigned short, h);
}
__device__ __forceinline__ float ftanh(float x) {   // clamped; |err|~1e-6
  float t = fminf(fmaxf(2.f * x, -30.f), 30.f);
  float e = __expf(t);
  return (e - 1.f) / (e + 1.f);
}

// ---------------------------------------------------------------- prep: win scan + weight frag convert
// grid (NWIN+3, B_SZ) x 128. Blocks w<NWIN: per-window Levy scan. Else: convert
// W1/W2/W3/Wl -> fp16 MFMA B-frag layout:
//   Wf[(kk*16+nsub)*64+lane][j] = W[nsub*16+(lane&15)][kk*32+(lane>>4)*8+j]
__global__ __launch_bounds__(128) void prep_kernel(
    const float* __restrict__ z,
    const float* __restrict__ W1, const float* __restrict__ W2,
    const float* __restrict__ W3, const float* __restrict__ Wl,
    float* __restrict__ logsig, float* __restrict__ dxwin,
    unsigned short* __restrict__ W1f, unsigned short* __restrict__ W2f,
    unsigned short* __restrict__ W3f, unsigned short* __restrict__ Wlf,
    SchedArgs A)
{
  const int w = blockIdx.x, b = blockIdx.y, tid = threadIdx.x;
  if (w >= NWIN) {                                   // ---- weight conversion
    const int slot = ((w - NWIN) * B_SZ + b) * 128 + tid;   // 196608 slots
    for (int e = slot; e < W1FN + 3 * WFN; e += 3 * B_SZ * 128) {
      if (e < W1FN) {
        int f = e;
        int j = f & 7, l15 = (f >> 3) & 15, lq = (f >> 7) & 3, nsub = (f >> 9) & 15, kk = f >> 13;
        int row = nsub * 16 + l15, col = kk * 32 + lq * 8 + j;
        float v = (col < HID + LSIG) ? W1[(size_t)row * (HID + LSIG) + col] : 0.f;
        W1f[f] = f2h(v);
      } else {
        int e2 = e - W1FN;
        int which = e2 >> 16, f = e2 & 65535;
        int j = f & 7, l15 = (f >> 3) & 15, lq = (f >> 7) & 3, nsub = (f >> 9) & 15, kk = (f >> 13) & 7;
        int row = nsub * 16 + l15, col = kk * 32 + lq * 8 + j;
        const float* src = which == 0 ? W2 : which == 1 ? W3 : Wl;
        unsigned short* dst = which == 0 ? W2f : which == 1 ? W3f : Wlf;
        dst[f] = f2h(src[(size_t)row * HID + col]);
      }
    }
    return;
  }
  // ---- per-window Levy scan (dtsqrt inlined)
  __shared__ float zs[50][16];
  const int ns = (w == NWIN - 1) ? 49 : 50;
  const float* src = z + ((size_t)b * SLEN + 50 * w + 1) * DD;
  const double s999 = 1.0 / (double)(SLEN - 1);
  for (int c = tid; c < ns * 4; c += 128) {
    float4 v = ((const float4*)src)[c];
    int t = 50 * w + (c >> 2);
    double a = (t + 1 == SLEN - 1) ? 1.0 : (double)(t + 1) * s999;
    float s = sqrtf((float)(a - (double)t * s999));
    v.x *= s; v.y *= s; v.z *= s; v.w *= s;
    ((float4*)&zs[0][0])[c] = v;
  }
  int pi = 0, pj = 0;
  if (tid < PAIRS) { int rem = tid, i = 0; while (rem >= DD - 1 - i) { rem -= DD - 1 - i; ++i; } pi = i; pj = i + 1 + rem; }
  __syncthreads();
  float Yi = 0.f, Yj = 0.f, LL = 0.f, Yd = 0.f;
  const int base_t = 50 * w;
  for (int u = 0; u < ns; ++u) {
    const float di = zs[u][pi], dj = zs[u][pj];
    LL = fmaf(Yi, dj, LL); LL = fmaf(-Yj, di, LL);
    Yi += di; Yj += dj;
    if (tid < DD) Yd += zs[u][tid];
    const int m = A.snapk[base_t + u];
    if (m) {
      float* dst = logsig + ((size_t)b * WIN + m) * LSIG;
      if (tid < DD)    dst[tid]      = Yd;
      if (tid < PAIRS) dst[DD + tid] = LL;
    }
  }
  if (tid < DD) dxwin[((size_t)b * NWIN + w) * DD + tid] = Yd;
}

// ---------------------------------------------------------------- combine + logsig partial (merged)
// grid (WIN, 32) x 256. Block (k, g): finalize logsig rows for 16 batches
// (b = 16g..16g+15) at window k (level-1 add + Levy adjust), then -- if k is
// an update step (sstep[k]!=255) -- compute the chain's L1 partial
// partial[g][s][row][col] = (W1s . logsig)[row][col] + b1[col] straight from
// LDS with swapped-operand MFMA (D[feature][batch]: lane&15 = batch row, each
// lane holds 4 consecutive out-cols -> row-major float4 store). Replaces the
// old comb_kernel + psig_kernel pair (one fewer dispatch, no logsig re-read).
__global__ __launch_bounds__(256) void combp_kernel(
    float* __restrict__ logsig, const float* __restrict__ dxwin,
    const unsigned short* __restrict__ W1f, const float* __restrict__ b1,
    float* __restrict__ partial, CombPArgs A)
{
  __shared__ float Xs[16][16], Yt[16][16];
  __shared__ __align__(16) unsigned short As[20 * 16 * 8];   // 160 cols, chunk-8
  const int k = blockIdx.x, g = blockIdx.y, tid = threadIdx.x;
  const int w = A.winofm[k], zl = A.zl[k], ss = A.sstep[k];
  for (int c = tid; c < 3 * 16 * 8; c += 256) As[17 * 16 * 8 + c] = 0;  // zero pad cols 136..159
  {                                                   // ---- level-1 (tid = bi*16+col)
    const int bi = tid >> 4, col = tid & 15;
    const size_t b = (size_t)(g * 16 + bi);
    float acc = 0.f;
    for (int ww = 0; ww < w; ++ww) acc += dxwin[(b * NWIN + ww) * DD + col];
    float y = (k == 0) ? 0.f : logsig[(b * WIN + k) * LSIG + col];
    float fin = (k == 0) ? 0.f : acc + y;
    Xs[bi][col] = acc; Yt[bi][col] = y;
    logsig[(b * WIN + k) * LSIG + col] = fin;
    As[((col >> 3) * 16 + bi) * 8 + (col & 7)] = f2h(fin);
  }
  __syncthreads();
  for (int idx = tid; idx < 16 * PAIRS; idx += 256) {  // ---- Levy pairs
    const int bi = idx / PAIRS, p = idx - bi * PAIRS;
    int rem = p, i = 0; while (rem >= DD - 1 - i) { rem -= DD - 1 - i; ++i; }
    const int pi = i, pj = i + 1 + rem;
    const size_t b = (size_t)(g * 16 + bi);
    float ll = (k == 0) ? 0.f : logsig[(b * WIN + k) * LSIG + DD + p];
    float fin = (k == 0 || zl) ? 0.f
              : 0.5f * (ll + Xs[bi][pi] * Yt[bi][pj] - Xs[bi][pj] * Yt[bi][pi]);
    logsig[(b * WIN + k) * LSIG + DD + p] = fin;
    const int c = DD + p;
    As[((c >> 3) * 16 + bi) * 8 + (c & 7)] = f2h(fin);
  }
  if (ss == 255) return;                               // uniform across block
  __syncthreads();
  const int lane = tid & 63, wv = tid >> 6;
  const int l15 = lane & 15, lq = lane >> 4;
  f32x4 acc4[4] = {{0,0,0,0},{0,0,0,0},{0,0,0,0},{0,0,0,0}};
#pragma unroll
  for (int kt = 0; kt < 5; ++kt) {
    half8 af = *(const half8*)&As[((kt * 4 + lq) * 16 + l15) * 8];
#pragma unroll
    for (int t = 0; t < 4; ++t) {
      half8 bfW = *(const half8*)(W1f + ((size_t)((8 + kt) * 16 + wv * 4 + t) * 64 + lane) * 8);
      acc4[t] = __builtin_amdgcn_mfma_f32_16x16x32_f16(bfW, af, acc4[t], 0, 0, 0);
    }
  }
#pragma unroll
  for (int t = 0; t < 4; ++t) {
    const int col0 = wv * 64 + t * 16 + lq * 4;
    f32x4 bb = *(const f32x4*)(b1 + col0);
    f32x4 r = acc4[t] + bb;
    *(f32x4*)&partial[(((size_t)g * PSTEP + ss) * 16 + l15) * HID + col0] = r;
  }
}

// ---------------------------------------------------------------- sequential state chain (fp16 MFMA)
// 32 blocks x 512 thr (8 waves). M=16 rows/block; wave w owns cols [32w,32w+32).
// All weights (48 half8 frags) resident in the unified VGPR/AGPR file
// (r1/r2 evidence: tiny FETCH). SWAPPED-OPERAND MFMA: D[feature][batch], so
// lane&15 = batch row and each lane holds 4 CONSECUTIVE out-cols -> epilogue
// is 2x ds_write_b64 per wave per layer (was 8x ds_write_b16) and state
// export is a packed 8B global store. LDS-pipe instr count per layer drops
// 128->80 per CU; that pipe was the per-step critical path. 3 barriers/step.
__global__ __attribute__((amdgpu_flat_work_group_size(512, 512)))
__attribute__((amdgpu_waves_per_eu(2, 2)))
void chain_kernel(
    const float* __restrict__ partial,
    const unsigned short* __restrict__ W1f, const unsigned short* __restrict__ W2f,
    const unsigned short* __restrict__ W3f,
    const float* __restrict__ b2, const float* __restrict__ b3,
    unsigned short* __restrict__ statesb, ChainArgs A)
{
  __shared__ __align__(16) unsigned short A0s[32 * 16 * 8];   // 8 KB (h, chunk-8)
  __shared__ __align__(16) unsigned short A1s[32 * 16 * 8];   // 8 KB
  __shared__ __align__(16) unsigned short A2s[32 * 16 * 8];   // 8 KB
  const int tid = threadIdx.x, g = blockIdx.x;
  const int lane = tid & 63, w = tid >> 6;
  const int l15 = lane & 15, lq = lane >> 4;

  for (int c = tid; c < 32 * 16 * 8; c += 512) A0s[c] = 0;
  for (int c = tid; c < 16 * HID; c += 512) {
    int r = c >> 8, col = c & 255;
    statesb[((size_t)(g * 16 + r) * MAXST + 0) * HID + col] = 0;
  }

  // ---- all weight frags -> registers (once, resident across all steps)
  half8 W1r[16], W2r[16], W3r[16];
#pragma unroll
  for (int kk = 0; kk < 8; ++kk)
#pragma unroll
    for (int nt = 0; nt < 2; ++nt) {
      W1r[kk * 2 + nt] = *(const half8*)(W1f + ((size_t)(kk * 16 + w * 2 + nt) * 64 + lane) * 8);
      W2r[kk * 2 + nt] = *(const half8*)(W2f + ((size_t)(kk * 16 + w * 2 + nt) * 64 + lane) * 8);
      W3r[kk * 2 + nt] = *(const half8*)(W3f + ((size_t)(kk * 16 + w * 2 + nt) * 64 + lane) * 8);
    }

  // per-lane column base (4 consecutive cols) for each n-tile
  int colb[2];
  f32x4 bias2v[2], bias3v[2];
#pragma unroll
  for (int nt = 0; nt < 2; ++nt) {
    colb[nt] = w * 32 + nt * 16 + lq * 4;
    bias2v[nt] = *(const f32x4*)(b2 + colb[nt]);
    bias3v[nt] = *(const f32x4*)(b3 + colb[nt]);
  }

  // partial prefetch plumbing (row-major [step][row16][256], float4/lane)
  const float* pbase = partial + (size_t)g * PSTEP * 16 * HID;
  int poff[2];
#pragma unroll
  for (int nt = 0; nt < 2; ++nt) poff[nt] = l15 * HID + colb[nt];
  f32x4 pf[2];
  pf[0] = *(const f32x4*)(pbase + poff[0]);
  pf[1] = *(const f32x4*)(pbase + poff[1]);

  short4v hv4[2];                                     // deferred packed state stores
  __syncthreads();                                    // A0s zeros visible

  for (int m = 0; m < A.nsteps; ++m) {
    if (m > 0) {                                      // store state m (from step m-1), 8B packed
#pragma unroll
      for (int nt = 0; nt < 2; ++nt)
        *(short4v*)&statesb[((size_t)(g * 16 + l15) * MAXST + m) * HID + colb[nt]] = hv4[nt];
    }
    // ---- L1: K=256 (h part), acc seeded from partial (has W1s.logsig + b1)
    {
      f32x4 acc[2][2];
      acc[0][0] = pf[0]; acc[0][1] = pf[1];
      acc[1][0] = (f32x4){0.f,0.f,0.f,0.f}; acc[1][1] = (f32x4){0.f,0.f,0.f,0.f};
      if (m + 1 < A.nsteps) {                         // prefetch next step's partial
        const float* pp = pbase + (size_t)(m + 1) * 16 * HID;
        pf[0] = *(const f32x4*)(pp + poff[0]);
        pf[1] = *(const f32x4*)(pp + poff[1]);
      }
#pragma unroll
      for (int kk = 0; kk < 8; ++kk) {
        half8 af = *(const half8*)&A0s[((kk * 4 + lq) * 16 + l15) * 8];
        acc[kk & 1][0] = __builtin_amdgcn_mfma_f32_16x16x32_f16(W1r[kk * 2    ], af, acc[kk & 1][0], 0, 0, 0);
        acc[kk & 1][1] = __builtin_amdgcn_mfma_f32_16x16x32_f16(W1r[kk * 2 + 1], af, acc[kk & 1][1], 0, 0, 0);
      }
#pragma unroll
      for (int nt = 0; nt < 2; ++nt) {
        f32x4 s = acc[0][nt] + acc[1][nt];
        short4v h4;
#pragma unroll
        for (int r4 = 0; r4 < 4; ++r4) h4[r4] = (short)f2h(fmaxf(s[r4], 0.f));
        *(short4v*)&A1s[((colb[nt] >> 3) * 16 + l15) * 8 + (colb[nt] & 7)] = h4;
      }
    }
    __syncthreads();
    // ---- L2: K=256, W2 from registers
    {
      f32x4 acc[2][2] = {{{0.f,0.f,0.f,0.f},{0.f,0.f,0.f,0.f}},{{0.f,0.f,0.f,0.f},{0.f,0.f,0.f,0.f}}};
#pragma unroll
      for (int kk = 0; kk < 8; ++kk) {
        half8 af = *(const half8*)&A1s[((kk * 4 + lq) * 16 + l15) * 8];
        acc[kk & 1][0] = __builtin_amdgcn_mfma_f32_16x16x32_f16(W2r[kk * 2    ], af, acc[kk & 1][0], 0, 0, 0);
        acc[kk & 1][1] = __builtin_amdgcn_mfma_f32_16x16x32_f16(W2r[kk * 2 + 1], af, acc[kk & 1][1], 0, 0, 0);
      }
#pragma unroll
      for (int nt = 0; nt < 2; ++nt) {
        f32x4 s = acc[0][nt] + acc[1][nt] + bias2v[nt];
        short4v h4;
#pragma unroll
        for (int r4 = 0; r4 < 4; ++r4) h4[r4] = (short)f2h(fmaxf(s[r4], 0.f));
        *(short4v*)&A2s[((colb[nt] >> 3) * 16 + l15) * 8 + (colb[nt] & 7)] = h4;
      }
    }
    __syncthreads();
    // ---- L3: K=256, W3 from registers; fast tanh -> A0 state; global store deferred
    {
      f32x4 acc[2][2] = {{{0.f,0.f,0.f,0.f},{0.f,0.f,0.f,0.f}},{{0.f,0.f,0.f,0.f},{0.f,0.f,0.f,0.f}}};
#pragma unroll
      for (int kk = 0; kk < 8; ++kk) {
        half8 af = *(const half8*)&A2s[((kk * 4 + lq) * 16 + l15) * 8];
        acc[kk & 1][0] = __builtin_amdgcn_mfma_f32_16x16x32_f16(W3r[kk * 2    ], af, acc[kk & 1][0], 0, 0, 0);
        acc[kk & 1][1] = __builtin_amdgcn_mfma_f32_16x16x32_f16(W3r[kk * 2 + 1], af, acc[kk & 1][1], 0, 0, 0);
      }
#pragma unroll
      for (int nt = 0; nt < 2; ++nt) {
        f32x4 s = acc[0][nt] + acc[1][nt] + bias3v[nt];
        short4v h4;
#pragma unroll
        for (int r4 = 0; r4 < 4; ++r4) h4[r4] = (short)f2h(ftanh(s[r4]));
        hv4[nt] = h4;
        *(short4v*)&A0s[((colb[nt] >> 3) * 16 + l15) * 8 + (colb[nt] & 7)] = h4;
      }
    }
    __syncthreads();
  }
  {                                                   // store final state (index nsteps)
    const int m = A.nsteps;
#pragma unroll
    for (int nt = 0; nt < 2; ++nt)
      *(short4v*)&statesb[((size_t)(g * 16 + l15) * MAXST + m) * HID + colb[nt]] = hv4[nt];
  }
}

// ---------------------------------------------------------------- fused batched MLP (fp16 MFMA)
// OCCUPANCY RESTRUCTURE (r4): grid 1024 x 256 thr. Block = 32 independent
// step-rows (half a batch row); wave w owns 64 cols x 32 rows -> acc[2][4].
// LDS = ONE 16 KB act buffer (reused in-place across layers; extra barrier
// between a layer's reads and the epilogue overwrite) + 2x2 KB staging
// = 20 KB -> 4 blocks/CU, 16 waves/CU, 4 waves/SIMD (was 144 KB -> 1 block/
// CU, 1 wave/SIMD, OccupancyPercent 9, MfmaUtil 13.5: pure latency exposure).
// W-frags re-read by 2x more blocks but L2-resident. Same math/layouts.
__global__ __launch_bounds__(256, 4) void fused_kernel(
    const unsigned short* __restrict__ statesb, const float* __restrict__ logsig,
    const unsigned short* __restrict__ W1f, const unsigned short* __restrict__ W2f,
    const unsigned short* __restrict__ W3f, const unsigned short* __restrict__ Wlf,
    const float* __restrict__ b1, const float* __restrict__ b2, const float* __restrict__ b3,
    float* __restrict__ out, FuseArgs F)
{
  __shared__ __align__(16) unsigned short act[32 * 32 * 8];     // 16 KB, chunk-8 [col>>3][row][col&7]
  __shared__ __align__(16) unsigned short atile[2][4 * 32 * 8]; // 2 x 2 KB
  const int tid = threadIdx.x;
  const int b = blockIdx.x >> 1, half = blockIdx.x & 1;
  const int lane = tid & 63, w = tid >> 6;
  const int l15 = lane & 15, lq = lane >> 4;

  f32x4 acc[2][4];
#pragma unroll
  for (int a = 0; a < 2; ++a)
#pragma unroll
    for (int t = 0; t < 4; ++t) acc[a][t] = (f32x4){0.f, 0.f, 0.f, 0.f};

  // ---- L1: K=416, A staged per-kk (dbuf, 1 barrier/kk), W-frags from L2
  const int lr = tid >> 3, lcc = (tid & 7) * 4;       // staging row / col-in-ktile
  const int lks = half * 32 + lr;
  short4v pk;
  auto loadA = [&](int kk) {
    int col = kk * 32 + lcc;
    if (col < HID) {
      pk = *(const short4v*)(statesb + ((size_t)b * MAXST + F.sidx[lks]) * HID + col);
    } else {
      const float* sp = logsig + ((size_t)b * WIN + lks) * LSIG + (col - HID); // tail reads past 136 benign (W pad=0)
      float4 v = *(const float4*)sp;
      short4v q;
      q[0] = (short)f2h(v.x); q[1] = (short)f2h(v.y); q[2] = (short)f2h(v.z); q[3] = (short)f2h(v.w);
      pk = q;
    }
  };
  loadA(0);
  for (int kk = 0; kk < 13; ++kk) {
    unsigned short* buf = &atile[kk & 1][0];
    *(short4v*)&buf[((lcc >> 3) * 32 + lr) * 8 + (lcc & 7)] = pk;
    __syncthreads();
    if (kk + 1 < 13) loadA(kk + 1);           // issue early; hides under MFMAs
    half8 bfr[4];
#pragma unroll
    for (int t = 0; t < 4; ++t)
      bfr[t] = *(const half8*)(W1f + ((size_t)(kk * 16 + w * 4 + t) * 64 + lane) * 8);
#pragma unroll
    for (int a = 0; a < 2; ++a) {
      half8 af = *(const half8*)&buf[(lq * 32 + a * 16 + l15) * 8];
#pragma unroll
      for (int t = 0; t < 4; ++t)
        acc[a][t] = __builtin_amdgcn_mfma_f32_16x16x32_f16(bfr[t], af, acc[a][t], 0, 0, 0);
    }
  }
#pragma unroll
  for (int t = 0; t < 4; ++t) {                       // L1 epilogue: relu+b1 -> act
    const int col0 = w * 64 + t * 16 + lq * 4;
    f32x4 bb = *(const f32x4*)(b1 + col0);
#pragma unroll
    for (int a = 0; a < 2; ++a) {
      const int row = a * 16 + l15;
      short4v h4;
#pragma unroll
      for (int r4 = 0; r4 < 4; ++r4) h4[r4] = (short)f2h(fmaxf(acc[a][t][r4] + bb[r4], 0.f));
      *(short4v*)&act[((col0 >> 3) * 32 + row) * 8 + (col0 & 7)] = h4;
    }
  }
  __syncthreads();

  // ---- generic K=256 layer: A from act LDS (in-place reuse), W-frags from L2
  auto layer = [&](const unsigned short* Wf) {
#pragma unroll
    for (int a = 0; a < 2; ++a)
#pragma unroll
      for (int t = 0; t < 4; ++t) acc[a][t] = (f32x4){0.f, 0.f, 0.f, 0.f};
    for (int kk = 0; kk < 8; ++kk) {
      half8 bfr[4];
#pragma unroll
      for (int t = 0; t < 4; ++t)
        bfr[t] = *(const half8*)(Wf + ((size_t)(kk * 16 + w * 4 + t) * 64 + lane) * 8);
#pragma unroll
      for (int a = 0; a < 2; ++a) {
        half8 af = *(const half8*)&act[((kk * 4 + lq) * 32 + a * 16 + l15) * 8];
#pragma unroll
        for (int t = 0; t < 4; ++t)
          acc[a][t] = __builtin_amdgcn_mfma_f32_16x16x32_f16(bfr[t], af, acc[a][t], 0, 0, 0);
      }
    }
  };

  layer(W2f);                                         // L2 -> relu -> act (in place)
  __syncthreads();                                    // all act reads done
#pragma unroll
  for (int t = 0; t < 4; ++t) {
    const int col0 = w * 64 + t * 16 + lq * 4;
    f32x4 bb = *(const f32x4*)(b2 + col0);
#pragma unroll
    for (int a = 0; a < 2; ++a) {
      const int row = a * 16 + l15;
      short4v h4;
#pragma unroll
      for (int r4 = 0; r4 < 4; ++r4) h4[r4] = (short)f2h(fmaxf(acc[a][t][r4] + bb[r4], 0.f));
      *(short4v*)&act[((col0 >> 3) * 32 + row) * 8 + (col0 & 7)] = h4;
    }
  }
  __syncthreads();

  layer(W3f);                                         // L3 -> tanh -> act (in place)
  __syncthreads();
#pragma unroll
  for (int t = 0; t < 4; ++t) {
    const int col0 = w * 64 + t * 16 + lq * 4;
    f32x4 bb = *(const f32x4*)(b3 + col0);
#pragma unroll
    for (int a = 0; a < 2; ++a) {
      const int row = a * 16 + l15;
      short4v h4;
#pragma unroll
      for (int r4 = 0; r4 < 4; ++r4) h4[r4] = (short)f2h(ftanh(acc[a][t][r4] + bb[r4]));
      *(short4v*)&act[((col0 >> 3) * 32 + row) * 8 + (col0 & 7)] = h4;
    }
  }
  __syncthreads();

  layer(Wlf);                                         // L4 -> fp32 out (float4 stores)
#pragma unroll
  for (int t = 0; t < 4; ++t) {
    const int col0 = w * 64 + t * 16 + lq * 4;
#pragma unroll
    for (int a = 0; a < 2; ++a) {
      const int ks = half * 32 + a * 16 + l15;
      *(f32x4*)&out[((size_t)b * WIN + ks) * HID + col0] = acc[a][t];
    }
  }
}

// ---------------------------------------------------------------- host schedule
static void build_sched(SchedArgs& P, CombPArgs& CB, ChainArgs& CH, FuseArgs& FU) {
  double tb[SLEN], tt[WIN], tu[NWIN];
  const double s999 = 1.0 / (double)(SLEN - 1);
  const double s63  = 1.0 / (double)(WIN - 1);
  for (int i = 0; i < SLEN; ++i) tb[i] = (double)i * s999;
  tb[SLEN - 1] = 1.0;
  for (int k = 0; k < WIN; ++k) tt[k] = (double)k * s63;
  tt[WIN - 1] = 1.0;
  for (int j = 0; j < NWIN; ++j) tu[j] = tb[50 * j];

  int t_idx[WIN - 1], u_for_t[WIN - 1];
  for (int k = 1; k < WIN; ++k) {
    int ii = 0;
    for (int q = 0; q < SLEN; ++q) if (tb[q] <= tt[k]) ii = q;
    t_idx[k - 1] = ii;
    int jj = 0;
    for (int q = 0; q < NWIN; ++q) if (tu[q] <= tt[k]) jj = q;
    u_for_t[k - 1] = jj;
  }
  for (int t = 0; t < SLEN - 1; ++t) P.snapk[t] = 0;
  for (int m = 1; m < WIN; ++m) P.snapk[t_idx[m - 1] - 1] = (short)m;

  for (int m = 0; m < WIN; ++m) { CB.winofm[m] = 0; CB.zl[m] = 0; CB.sstep[m] = 255; }
  for (int m = 1; m < WIN; ++m) {
    int p = t_idx[m - 1];
    CB.winofm[m] = (unsigned char)((p - 1) / 50);
    CB.zl[m] = (p % 50 == 0) ? 1 : 0;
  }

  double qt[32]; int nq = 0, last = -1;
  for (int m = 0; m < WIN - 1; ++m) {
    const int iu = u_for_t[m];
    if (iu != last) { qt[nq++] = tu[iu]; last = iu; }
  }
  qt[nq++] = tt[WIN - 1];
  int upd[WIN]; int qh = 0;
  for (int i = 0; i < WIN; ++i) {
    upd[i] = 0;
    if (qh < nq && tt[i] >= qt[qh]) { qh++; upd[i] = 1; }
  }
  int nU = 0;
  for (int k = 0; k < WIN; ++k) if (upd[k]) { if (nU < 32) CH.kU[nU] = (unsigned char)k; ++nU; }
  int cnt = 0;
  for (int k = 0; k < WIN; ++k) { FU.sidx[k] = (unsigned char)cnt; if (upd[k]) ++cnt; }
  CH.nsteps = FU.sidx[WIN - 1];
  for (int s = 0; s < nU && s < 32; ++s)
    if (s < PSTEP) CB.sstep[CH.kU[s]] = (unsigned char)s;
}

extern "C" void kernel_launch(void* const* d_in, const int* in_sizes, int n_in,
                              void* d_out, int out_size, void* d_ws, size_t ws_size,
                              hipStream_t stream) {
  const float* z  = (const float*)d_in[0];
  const float* W1 = (const float*)d_in[1];
  const float* b1 = (const float*)d_in[2];
  const float* W2 = (const float*)d_in[3];
  const float* b2 = (const float*)d_in[4];
  const float* W3 = (const float*)d_in[5];
  const float* b3 = (const float*)d_in[6];
  const float* Wl = (const float*)d_in[7];

  char* ws = (char*)d_ws;
  float* logsig = (float*)(ws);                                         // 17.83 MB
  size_t o = (size_t)B_SZ * WIN * LSIG * 4;
  float* dxwin            = (float*)(ws + o); o += (size_t)B_SZ * NWIN * DD * 4;
  unsigned short* statesb = (unsigned short*)(ws + o); o += (size_t)B_SZ * MAXST * HID * 2;
  unsigned short* W1f     = (unsigned short*)(ws + o); o += (size_t)W1FN * 2;
  unsigned short* W2f     = (unsigned short*)(ws + o); o += (size_t)WFN * 2;
  unsigned short* W3f     = (unsigned short*)(ws + o); o += (size_t)WFN * 2;
  unsigned short* Wlf     = (unsigned short*)(ws + o); o += (size_t)WFN * 2;
  float* partial          = (float*)(ws + o); o += (size_t)32 * PSTEP * 16 * HID * 4; // 11.0 MB

  SchedArgs P; CombPArgs CB; ChainArgs CH; FuseArgs FU;
  build_sched(P, CB, CH, FU);

  prep_kernel<<<dim3(NWIN + 3, B_SZ), 128, 0, stream>>>(
      z, W1, W2, W3, Wl, logsig, dxwin, W1f, W2f, W3f, Wlf, P);
  combp_kernel<<<dim3(WIN, 32), 256, 0, stream>>>(logsig, dxwin, W1f, b1, partial, CB);
  chain_kernel<<<32, 512, 0, stream>>>(partial, W1f, W2f, W3f, b2, b3, statesb, CH);
  fused_kernel<<<1024, 256, 0, stream>>>(statesb, logsig, W1f, W2f, W3f, Wlf,
                                         b1, b2, b3, (float*)d_out, FU);
}